// Round 6
// baseline (104.011 us; speedup 1.0000x reference)
//
#include <hip/hip_runtime.h>
#include <hip/hip_bf16.h>

#define NFFT 1024
#define HOP 256
#define NB 16
#define NT 1024
#define KA 512                     // K = freqs 0..511 (f=512 via re512 rank-1 term)
#define MM (NB*NT)                 // 16384
#define LOUT ((NT-1)*HOP + NFFT)   // 262912
#define CQ (2.0f/(3.0f*1024.0f))   // (HOP/sum(win^2))/NFFT

typedef __bf16 bf16x8 __attribute__((ext_vector_type(8)));
typedef __bf16 bf16x4 __attribute__((ext_vector_type(4)));
typedef float f32x4 __attribute__((ext_vector_type(4)));

__device__ __forceinline__ void gload_lds16(const void* g, void* l) {
  __builtin_amdgcn_global_load_lds(
      (const __attribute__((address_space(1))) void*)g,
      (__attribute__((address_space(3))) void*)l, 16, 0, 0);
}

// Bc[n][f] = sc_f*cos(2pi f n/1024)*CQ*win[n]; Bs likewise with sin. win folded in.
// s_tab[n] = (-1)^n * win[n] * CQ   (the f=512 rank-1 column factor)
__global__ void build_B(__hip_bfloat16* __restrict__ Bc, __hip_bfloat16* __restrict__ Bs,
                        float* __restrict__ s_tab) {
  int idx = blockIdx.x * 256 + threadIdx.x;   // 512*512
  int n = idx >> 9;
  int f = idx & 511;
  int ph = (f * n) & 1023;
  const float w0 = 6.283185307179586f / 1024.f;
  float si, co;
  __sincosf((float)ph * w0, &si, &co);
  float wn = 0.5f - 0.5f * __cosf((float)n * w0);
  float sc = (f == 0) ? 1.f : 2.f;
  float b = sc * CQ * wn;
  Bc[idx] = __float2bfloat16(co * b);
  Bs[idx] = __float2bfloat16(si * b);
  if (idx < 512) {
    float wn2 = 0.5f - 0.5f * __cosf((float)idx * w0);
    s_tab[idx] = ((idx & 1) ? -1.f : 1.f) * wn2 * CQ;
  }
}

// Are[b*1024+t][f] = x[b][f][t][0], Aim = [..][1]; re512[m] = x[b][512][t][0]
__global__ void pack_a(const float* __restrict__ x,
                       __hip_bfloat16* __restrict__ Are, __hip_bfloat16* __restrict__ Aim,
                       float* __restrict__ re512) {
  __shared__ float2 tile[64][65];
  int b = blockIdx.z, f0 = blockIdx.y * 64, t0 = blockIdx.x * 64;
  int tid = threadIdx.x;
  int tl = tid & 63, th = tid >> 6;
#pragma unroll
  for (int r = 0; r < 16; ++r) {
    int fl = r * 4 + th;
    tile[fl][tl] = *(const float2*)(x + (((size_t)b * 513 + f0 + fl) * 1024 + (t0 + tl)) * 2);
  }
  __syncthreads();
  int row = tid >> 2;                // t-local 0..63
#pragma unroll
  for (int i = 0; i < 4; ++i) {
    int chunk = (tid & 3) * 4 + i;   // 0..15 -> f-quad
    float2 v0 = tile[chunk * 4 + 0][row];
    float2 v1 = tile[chunk * 4 + 1][row];
    float2 v2 = tile[chunk * 4 + 2][row];
    float2 v3 = tile[chunk * 4 + 3][row];
    bf16x4 pr, pi;
    pr[0] = (__bf16)v0.x; pr[1] = (__bf16)v1.x; pr[2] = (__bf16)v2.x; pr[3] = (__bf16)v3.x;
    pi[0] = (__bf16)v0.y; pi[1] = (__bf16)v1.y; pi[2] = (__bf16)v2.y; pi[3] = (__bf16)v3.y;
    size_t rowm = (size_t)(b * 1024 + t0 + row) * KA + f0 + chunk * 4;
    *(bf16x4*)(Are + rowm) = pr;
    *(bf16x4*)(Aim + rowm) = pi;
  }
  if (blockIdx.y == 0 && tid < 64)
    re512[b * 1024 + t0 + tid] = x[(((size_t)b * 513 + 512) * 1024 + t0 + tid) * 2];
}

// fr512[m] = CQ * (re0 + re512 + sum_{f=1..511} 2*(-1)^f re_f)   (win[512]=1)
__global__ void nyq(const __hip_bfloat16* __restrict__ Are, const float* __restrict__ re512,
                    float* __restrict__ fr512) {
  int tid = threadIdx.x;
  int lane = tid & 63;
  int row = blockIdx.x * 4 + (tid >> 6);
  const bf16x8 v = *(const bf16x8*)&Are[(size_t)row * KA + lane * 8];
  float s = 0.f;
#pragma unroll
  for (int e = 0; e < 8; ++e) {
    int f = lane * 8 + e;
    float w = (f == 0) ? 1.f : ((f & 1) ? -2.f : 2.f);
    s += w * (float)v[e];
  }
#pragma unroll
  for (int off = 32; off >= 1; off >>= 1) s += __shfl_xor(s, off, 64);
  if (lane == 0) fr512[row] = (s + re512[row]) * CQ;
}

// U = Are*Bc^T, V = Aim*Bs^T (win folded in B). A-fragments loaded DIRECTLY from
// global (L2/L3-hot); only B (1 MB, L2-resident) is LDS-staged, BK=64, dbuf.
// Wave wv owns m-rows [wv*32, wv*32+32) x all 128 n-cols of the block.
// B LDS slot-swizzle: LDS[row][slot] = G[row][slot ^ (row&7)], slot = 8-elem group.
__global__ __launch_bounds__(256) void gemm_uv(
    const __hip_bfloat16* __restrict__ Are, const __hip_bfloat16* __restrict__ Aim,
    const __hip_bfloat16* __restrict__ Bc, const __hip_bfloat16* __restrict__ Bs,
    const float* __restrict__ re512, const float* __restrict__ s_tab,
    __hip_bfloat16* __restrict__ frames0, __hip_bfloat16* __restrict__ frames1) {
  __shared__ __align__(16) __hip_bfloat16 smem[32768];  // 64KB: [2 buf][2 mat][128][64]
  int tid = threadIdx.x;
  int lane = tid & 63;
  int wv = tid >> 6;
  int wm = wv * 32;
  int M0 = blockIdx.x * 128;
  int N0 = blockIdx.y * 128;

  f32x4 aU[2][8] = {};
  f32x4 aV[2][8] = {};

  const int srow = tid >> 3;       // 0..31
  const int ssq = tid & 7;         // dest slot (linear: dest byte = p*4096 + tid*16)

#define STAGE_B(KT, BB)                                                        \
  {                                                                            \
    int k0 = (KT) * 64;                                                        \
    _Pragma("unroll")                                                          \
    for (int p = 0; p < 4; ++p) {                                              \
      int row = p * 32 + srow;                                                 \
      int ksl = (ssq ^ (row & 7)) * 8;                                         \
      int lo = (BB) * 16384 + row * 64 + ssq * 8;                              \
      gload_lds16(Bc + (size_t)(N0 + row) * KA + k0 + ksl, &smem[lo]);         \
      gload_lds16(Bs + (size_t)(N0 + row) * KA + k0 + ksl, &smem[8192 + lo]);  \
    }                                                                          \
  }

  STAGE_B(0, 0);
  __syncthreads();

  for (int kt = 0; kt < 8; ++kt) {
    int cur = kt & 1;
    // A fragments for this k-step: direct global->VGPR (each m-row owned by 1 wave)
    bf16x8 ar[2][2], ai[2][2];     // [ks][mi]
#pragma unroll
    for (int ks = 0; ks < 2; ++ks)
#pragma unroll
      for (int mi = 0; mi < 2; ++mi) {
        size_t ga = (size_t)(M0 + wm + mi * 16 + (lane & 15)) * KA
                    + kt * 64 + ks * 32 + (lane >> 4) * 8;
        ar[ks][mi] = *(const bf16x8*)(Are + ga);
        ai[ks][mi] = *(const bf16x8*)(Aim + ga);
      }
    if (kt + 1 < 8) STAGE_B(kt + 1, cur ^ 1);

    const __hip_bfloat16* bc = smem + cur * 16384;
    const __hip_bfloat16* bs = bc + 8192;
#pragma unroll
    for (int ks = 0; ks < 2; ++ks) {
#pragma unroll
      for (int ni = 0; ni < 8; ++ni) {
        int row = ni * 16 + (lane & 15);
        int sl = ((ks * 4 + (lane >> 4)) ^ (row & 7)) * 8;
        bf16x8 bcf = *(const bf16x8*)&bc[row * 64 + sl];
#pragma unroll
        for (int mi = 0; mi < 2; ++mi)
          aU[mi][ni] = __builtin_amdgcn_mfma_f32_16x16x32_bf16(
              ar[ks][mi], bcf, aU[mi][ni], 0, 0, 0);
        bf16x8 bsf = *(const bf16x8*)&bs[row * 64 + sl];
#pragma unroll
        for (int mi = 0; mi < 2; ++mi)
          aV[mi][ni] = __builtin_amdgcn_mfma_f32_16x16x32_bf16(
              ai[ks][mi], bsf, aV[mi][ni], 0, 0, 0);
      }
    }
    __syncthreads();               // stage(kt+1) drained; buf swap safe
  }

  // epilogue: fragments -> LDS (granule-swizzled) -> coalesced bf16 stores
  __hip_bfloat16* fr0 = smem;
  __hip_bfloat16* fr1 = smem + 16384;
  float sn[8];
#pragma unroll
  for (int ni = 0; ni < 8; ++ni)
    sn[ni] = s_tab[N0 + ni * 16 + (lane & 15)];
#pragma unroll
  for (int mi = 0; mi < 2; ++mi) {
#pragma unroll
    for (int r = 0; r < 4; ++r) {
      int rl = wm + mi * 16 + (lane >> 4) * 4 + r;
      float rv = re512[M0 + rl];
      int rx = (rl & 7) << 3;
#pragma unroll
      for (int ni = 0; ni < 8; ++ni) {
        int cl = ni * 16 + (lane & 15);
        float U = aU[mi][ni][r], V = aV[mi][ni][r];
        float add = rv * sn[ni];
        int c2 = 127 - cl;
        fr0[rl * 128 + ((cl & ~7) ^ rx) + (cl & 7)] = __float2bfloat16(U - V + add);
        fr1[rl * 128 + ((c2 & ~7) ^ rx) + (c2 & 7)] = __float2bfloat16(U + V + add);
      }
    }
  }
  __syncthreads();
  int row = tid >> 1;
  int g0 = (tid & 1) * 8;
  size_t m = (size_t)(M0 + row);
  const int4* s0 = (const int4*)fr0;
  const int4* s1 = (const int4*)fr1;
  int4* d0 = (int4*)(frames0 + m * 512 + N0 + g0 * 8);
  int4* d1 = (int4*)(frames1 + m * 512 + (384 - N0) + g0 * 8);
#pragma unroll
  for (int c = 0; c < 8; ++c) {
    int q = (g0 + c) ^ (row & 7);
    d0[c] = s0[row * 16 + q];
    d1[c] = s1[row * 16 + q];
  }
}

// out[b][l] = sum_t frame[t][l-256t]; j<512 -> frames0[m][j], j==512 -> fr512[m],
// j>512 -> frames1[m][j-513]
__global__ void ola(const __hip_bfloat16* __restrict__ frames0,
                    const __hip_bfloat16* __restrict__ frames1,
                    const float* __restrict__ fr512, float* __restrict__ out, int total) {
  int idx = blockIdx.x * blockDim.x + threadIdx.x;
  int stride = gridDim.x * blockDim.x;
  for (; idx < total; idx += stride) {
    int b = idx / LOUT;
    int l = idx - b * LOUT;
    int thi = l >> 8; if (thi > NT - 1) thi = NT - 1;
    int tlo = (l - 768) >> 8; if (tlo < 0) tlo = 0;
    float s = 0.f;
    for (int t = tlo; t <= thi; ++t) {
      int j = l - (t << 8);
      size_t m = (size_t)b * NT + t;
      if (j < 512) s += __bfloat162float(frames0[m * 512 + j]);
      else if (j > 512) s += __bfloat162float(frames1[m * 512 + (j - 513)]);
      else s += fr512[m];
    }
    out[idx] = s;
  }
}

extern "C" void kernel_launch(void* const* d_in, const int* in_sizes, int n_in,
                              void* d_out, int out_size, void* d_ws, size_t ws_size,
                              hipStream_t stream) {
  (void)in_sizes; (void)n_in; (void)out_size; (void)ws_size;
  const float* x = (const float*)d_in[0];
  float* out = (float*)d_out;
  char* ws = (char*)d_ws;
  size_t oAre = 0;
  size_t oAim = oAre + (size_t)MM * KA * 2;
  size_t oBc  = oAim + (size_t)MM * KA * 2;
  size_t oBs  = oBc + (size_t)512 * 512 * 2;
  size_t oS   = oBs + (size_t)512 * 512 * 2;
  size_t oR5  = oS + 512 * 4;
  size_t oF5  = oR5 + (size_t)MM * 4;
  size_t oF0  = oF5 + (size_t)MM * 4;
  size_t oF1  = oF0 + (size_t)MM * 512 * 2;
  __hip_bfloat16* Are = (__hip_bfloat16*)(ws + oAre);
  __hip_bfloat16* Aim = (__hip_bfloat16*)(ws + oAim);
  __hip_bfloat16* Bc  = (__hip_bfloat16*)(ws + oBc);
  __hip_bfloat16* Bs  = (__hip_bfloat16*)(ws + oBs);
  float* s_tab = (float*)(ws + oS);
  float* re512 = (float*)(ws + oR5);
  float* fr512 = (float*)(ws + oF5);
  __hip_bfloat16* frames0 = (__hip_bfloat16*)(ws + oF0);
  __hip_bfloat16* frames1 = (__hip_bfloat16*)(ws + oF1);

  build_B<<<dim3(512 * 512 / 256), dim3(256), 0, stream>>>(Bc, Bs, s_tab);
  pack_a<<<dim3(16, 8, 16), dim3(256), 0, stream>>>(x, Are, Aim, re512);
  nyq<<<dim3(MM / 4), dim3(256), 0, stream>>>(Are, re512, fr512);
  gemm_uv<<<dim3(MM / 128, 4), dim3(256), 0, stream>>>(Are, Aim, Bc, Bs, re512, s_tab,
                                                       frames0, frames1);
  ola<<<dim3(2048), dim3(256), 0, stream>>>(frames0, frames1, fr512, out, NB * LOUT);
}

// Round 7
// 91.247 us; speedup vs baseline: 1.1399x; 1.1399x over previous
//
#include <hip/hip_runtime.h>
#include <hip/hip_bf16.h>

#define NFFT 1024
#define HOP 256
#define NB 16
#define NT 1024
#define KA 512                     // K = freqs 0..511 (f=512 via re512 rank-1 term)
#define MM (NB*NT)                 // 16384
#define LOUT ((NT-1)*HOP + NFFT)   // 262912
#define CQ (2.0f/(3.0f*1024.0f))   // (HOP/sum(win^2))/NFFT

typedef __bf16 bf16x8 __attribute__((ext_vector_type(8)));
typedef __bf16 bf16x4 __attribute__((ext_vector_type(4)));
typedef float f32x4 __attribute__((ext_vector_type(4)));

__device__ __forceinline__ void gload_lds16(const void* g, void* l) {
  __builtin_amdgcn_global_load_lds(
      (const __attribute__((address_space(1))) void*)g,
      (__attribute__((address_space(3))) void*)l, 16, 0, 0);
}

// Bc[n][f] = sc_f*cos(2pi f n/1024)*CQ*win[n]; Bs likewise with sin. win folded in.
// s_tab[n] = (-1)^n * win[n] * CQ   (the f=512 rank-1 column factor)
__global__ void build_B(__hip_bfloat16* __restrict__ Bc, __hip_bfloat16* __restrict__ Bs,
                        float* __restrict__ s_tab) {
  int idx = blockIdx.x * 256 + threadIdx.x;   // 512*512
  int n = idx >> 9;
  int f = idx & 511;
  int ph = (f * n) & 1023;
  const float w0 = 6.283185307179586f / 1024.f;
  float si, co;
  __sincosf((float)ph * w0, &si, &co);
  float wn = 0.5f - 0.5f * __cosf((float)n * w0);
  float sc = (f == 0) ? 1.f : 2.f;
  float b = sc * CQ * wn;
  Bc[idx] = __float2bfloat16(co * b);
  Bs[idx] = __float2bfloat16(si * b);
  if (idx < 512) {
    float wn2 = 0.5f - 0.5f * __cosf((float)idx * w0);
    s_tab[idx] = ((idx & 1) ? -1.f : 1.f) * wn2 * CQ;
  }
}

// Are[b*1024+t][f] = x[b][f][t][0], Aim = [..][1]; re512[m] = x[b][512][t][0]
__global__ void pack_a(const float* __restrict__ x,
                       __hip_bfloat16* __restrict__ Are, __hip_bfloat16* __restrict__ Aim,
                       float* __restrict__ re512) {
  __shared__ float2 tile[64][65];
  int b = blockIdx.z, f0 = blockIdx.y * 64, t0 = blockIdx.x * 64;
  int tid = threadIdx.x;
  int tl = tid & 63, th = tid >> 6;
#pragma unroll
  for (int r = 0; r < 16; ++r) {
    int fl = r * 4 + th;
    tile[fl][tl] = *(const float2*)(x + (((size_t)b * 513 + f0 + fl) * 1024 + (t0 + tl)) * 2);
  }
  __syncthreads();
  int row = tid >> 2;                // t-local 0..63
#pragma unroll
  for (int i = 0; i < 4; ++i) {
    int chunk = (tid & 3) * 4 + i;   // 0..15 -> f-quad
    float2 v0 = tile[chunk * 4 + 0][row];
    float2 v1 = tile[chunk * 4 + 1][row];
    float2 v2 = tile[chunk * 4 + 2][row];
    float2 v3 = tile[chunk * 4 + 3][row];
    bf16x4 pr, pi;
    pr[0] = (__bf16)v0.x; pr[1] = (__bf16)v1.x; pr[2] = (__bf16)v2.x; pr[3] = (__bf16)v3.x;
    pi[0] = (__bf16)v0.y; pi[1] = (__bf16)v1.y; pi[2] = (__bf16)v2.y; pi[3] = (__bf16)v3.y;
    size_t rowm = (size_t)(b * 1024 + t0 + row) * KA + f0 + chunk * 4;
    *(bf16x4*)(Are + rowm) = pr;
    *(bf16x4*)(Aim + rowm) = pi;
  }
  if (blockIdx.y == 0 && tid < 64)
    re512[b * 1024 + t0 + tid] = x[(((size_t)b * 513 + 512) * 1024 + t0 + tid) * 2];
}

// fr512[m] = CQ * (re0 + re512 + sum_{f=1..511} 2*(-1)^f re_f)   (win[512]=1)
__global__ void nyq(const __hip_bfloat16* __restrict__ Are, const float* __restrict__ re512,
                    float* __restrict__ fr512) {
  int tid = threadIdx.x;
  int lane = tid & 63;
  int row = blockIdx.x * 4 + (tid >> 6);
  const bf16x8 v = *(const bf16x8*)&Are[(size_t)row * KA + lane * 8];
  float s = 0.f;
#pragma unroll
  for (int e = 0; e < 8; ++e) {
    int f = lane * 8 + e;
    float w = (f == 0) ? 1.f : ((f & 1) ? -2.f : 2.f);
    s += w * (float)v[e];
  }
#pragma unroll
  for (int off = 32; off >= 1; off >>= 1) s += __shfl_xor(s, off, 64);
  if (lane == 0) fr512[row] = (s + re512[row]) * CQ;
}

// U = Are*Bc^T, V = Aim*Bs^T (win folded in B). 128m x 64n tile, BK=32, dbuf,
// 24KB/buf (48KB LDS -> 3 blocks/CU). Slot-swizzle: LDS[row][q] = G[row][q^((row>>1)&3)].
// frames0[m][n] = U-V+re512*s[n] (n<512), frames1[m][511-n] = U+V+re512*s[n].
__global__ __launch_bounds__(256) void gemm_uv(
    const __hip_bfloat16* __restrict__ Are, const __hip_bfloat16* __restrict__ Aim,
    const __hip_bfloat16* __restrict__ Bc, const __hip_bfloat16* __restrict__ Bs,
    const float* __restrict__ re512, const float* __restrict__ s_tab,
    __hip_bfloat16* __restrict__ frames0, __hip_bfloat16* __restrict__ frames1) {
  __shared__ __align__(16) __hip_bfloat16 smem[24576];  // 48KB: 2 bufs x 24KB
  int tid = threadIdx.x;
  int lane = tid & 63;
  int wv = tid >> 6;
  int wm = (wv >> 1) * 64;         // wave m-offset (2x2 wave grid of 64m x 32n)
  int wn = (wv & 1) * 32;
  int M0 = blockIdx.x * 128;
  int N0 = blockIdx.y * 64;

  f32x4 aU[4][2] = {};
  f32x4 aV[4][2] = {};

  const int sq = tid & 3;          // dest slot (dest byte offset = tid*16 within matrix)

  // buf layout (elems): sAr [0,4096) sAi [4096,8192) sBc [8192,10240) sBs [10240,12288)
#define STAGE(KT, BB)                                                            \
  {                                                                              \
    int k0 = (KT) * 32;                                                          \
    _Pragma("unroll")                                                            \
    for (int p = 0; p < 2; ++p) {                                                \
      int row = p * 64 + (tid >> 2);                                             \
      int ksl = (sq ^ ((row >> 1) & 3)) * 8;                                     \
      int lo = (BB) * 12288 + row * 32 + sq * 8;                                 \
      gload_lds16(Are + (size_t)(M0 + row) * KA + k0 + ksl, &smem[lo]);          \
      gload_lds16(Aim + (size_t)(M0 + row) * KA + k0 + ksl, &smem[lo + 4096]);   \
    }                                                                            \
    {                                                                            \
      int row = tid >> 2;                                                        \
      int ksl = (sq ^ ((row >> 1) & 3)) * 8;                                     \
      int lo = (BB) * 12288 + 8192 + row * 32 + sq * 8;                          \
      gload_lds16(Bc + (size_t)(N0 + row) * KA + k0 + ksl, &smem[lo]);           \
      gload_lds16(Bs + (size_t)(N0 + row) * KA + k0 + ksl, &smem[lo + 2048]);    \
    }                                                                            \
  }

  STAGE(0, 0);
  __syncthreads();

  const int fs = lane >> 4;        // requested k-slot for fragments
  const int arow[4] = {wm + 0 + (lane & 15), wm + 16 + (lane & 15),
                       wm + 32 + (lane & 15), wm + 48 + (lane & 15)};
  const int brow[2] = {wn + 0 + (lane & 15), wn + 16 + (lane & 15)};

  for (int kt = 0; kt < 16; ++kt) {
    int cur = (kt & 1) * 12288;
    if (kt + 1 < 16) STAGE(kt + 1, (kt & 1) ^ 1);
    const __hip_bfloat16* sAr = smem + cur;
    const __hip_bfloat16* sAi = smem + cur + 4096;
    const __hip_bfloat16* sBc = smem + cur + 8192;
    const __hip_bfloat16* sBs = smem + cur + 10240;
    bf16x8 af[4], bfr[2];
#pragma unroll
    for (int mi = 0; mi < 4; ++mi)
      af[mi] = *(const bf16x8*)&sAr[arow[mi] * 32 + (fs ^ ((arow[mi] >> 1) & 3)) * 8];
#pragma unroll
    for (int ni = 0; ni < 2; ++ni)
      bfr[ni] = *(const bf16x8*)&sBc[brow[ni] * 32 + (fs ^ ((brow[ni] >> 1) & 3)) * 8];
#pragma unroll
    for (int mi = 0; mi < 4; ++mi)
#pragma unroll
      for (int ni = 0; ni < 2; ++ni)
        aU[mi][ni] = __builtin_amdgcn_mfma_f32_16x16x32_bf16(
            af[mi], bfr[ni], aU[mi][ni], 0, 0, 0);
#pragma unroll
    for (int mi = 0; mi < 4; ++mi)
      af[mi] = *(const bf16x8*)&sAi[arow[mi] * 32 + (fs ^ ((arow[mi] >> 1) & 3)) * 8];
#pragma unroll
    for (int ni = 0; ni < 2; ++ni)
      bfr[ni] = *(const bf16x8*)&sBs[brow[ni] * 32 + (fs ^ ((brow[ni] >> 1) & 3)) * 8];
#pragma unroll
    for (int mi = 0; mi < 4; ++mi)
#pragma unroll
      for (int ni = 0; ni < 2; ++ni)
        aV[mi][ni] = __builtin_amdgcn_mfma_f32_16x16x32_bf16(
            af[mi], bfr[ni], aV[mi][ni], 0, 0, 0);
    __syncthreads();               // stage(kt+1) drained; buf swap safe
  }

  // epilogue: fragments -> LDS (granule-swizzled, rows of 64) -> coalesced bf16 stores
  __hip_bfloat16* fr0 = smem;
  __hip_bfloat16* fr1 = smem + 8192;
  float sn[2];
#pragma unroll
  for (int ni = 0; ni < 2; ++ni)
    sn[ni] = s_tab[N0 + wn + ni * 16 + (lane & 15)];
#pragma unroll
  for (int mi = 0; mi < 4; ++mi) {
#pragma unroll
    for (int r = 0; r < 4; ++r) {
      int rl = wm + mi * 16 + (lane >> 4) * 4 + r;
      float rv = re512[M0 + rl];
      int rx = (rl & 7) << 3;
#pragma unroll
      for (int ni = 0; ni < 2; ++ni) {
        int cl = wn + ni * 16 + (lane & 15);
        float U = aU[mi][ni][r], V = aV[mi][ni][r];
        float add = rv * sn[ni];
        int c2 = 63 - cl;
        fr0[rl * 64 + ((cl & ~7) ^ rx) + (cl & 7)] = __float2bfloat16(U - V + add);
        fr1[rl * 64 + ((c2 & ~7) ^ rx) + (c2 & 7)] = __float2bfloat16(U + V + add);
      }
    }
  }
  __syncthreads();
  int row = tid >> 1;              // 0..127
  int g0 = (tid & 1) * 4;          // first int4-granule of this half-row
  size_t m = (size_t)(M0 + row);
  const int4* s0 = (const int4*)fr0;
  const int4* s1 = (const int4*)fr1;
  int4* d0 = (int4*)(frames0 + m * 512 + N0 + g0 * 8);
  int4* d1 = (int4*)(frames1 + m * 512 + (448 - N0) + g0 * 8);
#pragma unroll
  for (int c = 0; c < 4; ++c) {
    int q = (g0 + c) ^ (row & 7);
    d0[c] = s0[row * 8 + q];
    d1[c] = s1[row * 8 + q];
  }
}

// out[b][l] = sum_t frame[t][l-256t]; j<512 -> frames0[m][j], j==512 -> fr512[m],
// j>512 -> frames1[m][j-513]
__global__ void ola(const __hip_bfloat16* __restrict__ frames0,
                    const __hip_bfloat16* __restrict__ frames1,
                    const float* __restrict__ fr512, float* __restrict__ out, int total) {
  int idx = blockIdx.x * blockDim.x + threadIdx.x;
  int stride = gridDim.x * blockDim.x;
  for (; idx < total; idx += stride) {
    int b = idx / LOUT;
    int l = idx - b * LOUT;
    int thi = l >> 8; if (thi > NT - 1) thi = NT - 1;
    int tlo = (l - 768) >> 8; if (tlo < 0) tlo = 0;
    float s = 0.f;
    for (int t = tlo; t <= thi; ++t) {
      int j = l - (t << 8);
      size_t m = (size_t)b * NT + t;
      if (j < 512) s += __bfloat162float(frames0[m * 512 + j]);
      else if (j > 512) s += __bfloat162float(frames1[m * 512 + (j - 513)]);
      else s += fr512[m];
    }
    out[idx] = s;
  }
}

extern "C" void kernel_launch(void* const* d_in, const int* in_sizes, int n_in,
                              void* d_out, int out_size, void* d_ws, size_t ws_size,
                              hipStream_t stream) {
  (void)in_sizes; (void)n_in; (void)out_size; (void)ws_size;
  const float* x = (const float*)d_in[0];
  float* out = (float*)d_out;
  char* ws = (char*)d_ws;
  size_t oAre = 0;
  size_t oAim = oAre + (size_t)MM * KA * 2;
  size_t oBc  = oAim + (size_t)MM * KA * 2;
  size_t oBs  = oBc + (size_t)512 * 512 * 2;
  size_t oS   = oBs + (size_t)512 * 512 * 2;
  size_t oR5  = oS + 512 * 4;
  size_t oF5  = oR5 + (size_t)MM * 4;
  size_t oF0  = oF5 + (size_t)MM * 4;
  size_t oF1  = oF0 + (size_t)MM * 512 * 2;
  __hip_bfloat16* Are = (__hip_bfloat16*)(ws + oAre);
  __hip_bfloat16* Aim = (__hip_bfloat16*)(ws + oAim);
  __hip_bfloat16* Bc  = (__hip_bfloat16*)(ws + oBc);
  __hip_bfloat16* Bs  = (__hip_bfloat16*)(ws + oBs);
  float* s_tab = (float*)(ws + oS);
  float* re512 = (float*)(ws + oR5);
  float* fr512 = (float*)(ws + oF5);
  __hip_bfloat16* frames0 = (__hip_bfloat16*)(ws + oF0);
  __hip_bfloat16* frames1 = (__hip_bfloat16*)(ws + oF1);

  build_B<<<dim3(512 * 512 / 256), dim3(256), 0, stream>>>(Bc, Bs, s_tab);
  pack_a<<<dim3(16, 8, 16), dim3(256), 0, stream>>>(x, Are, Aim, re512);
  nyq<<<dim3(MM / 4), dim3(256), 0, stream>>>(Are, re512, fr512);
  gemm_uv<<<dim3(MM / 128, 8), dim3(256), 0, stream>>>(Are, Aim, Bc, Bs, re512, s_tab,
                                                       frames0, frames1);
  ola<<<dim3(2048), dim3(256), 0, stream>>>(frames0, frames1, fr512, out, NB * LOUT);
}

// Round 8
// 90.362 us; speedup vs baseline: 1.1511x; 1.0098x over previous
//
#include <hip/hip_runtime.h>
#include <hip/hip_bf16.h>

#define HOP 256
#define NB 16
#define NT 1024
#define KA 512                     // K = freqs 0..511 (f=512 via rank-1 term)
#define MM (NB*NT)                 // 16384
#define LOUT ((NT-1)*HOP + 1024)   // 262912
#define CQ (2.0f/(3.0f*1024.0f))   // (HOP/sum(win^2))/NFFT
#define NKER 640                   // ker rows: 0..512 real, 513..639 zero pad

typedef __bf16 bf16x8 __attribute__((ext_vector_type(8)));
typedef float f32x4 __attribute__((ext_vector_type(4)));

__device__ __forceinline__ void gload_lds16(const void* g, void* l) {
  __builtin_amdgcn_global_load_lds(
      (const __attribute__((address_space(1))) void*)g,
      (__attribute__((address_space(3))) void*)l, 16, 0, 0);
}

// kerc[n][f] = sc_f*cos(2pi f n/1024)*CQ*win[n]; kers likewise sin. win folded.
// Row 512 = Nyquist weights (win[512]=1, cos(pi f)=+-1). Rows 513..639 zero.
// s_tab[n] = (-1)^n * win[n] * CQ for n<=512, else 0.
__global__ void build_B(__hip_bfloat16* __restrict__ Bc, __hip_bfloat16* __restrict__ Bs,
                        float* __restrict__ s_tab) {
  int idx = blockIdx.x * 256 + threadIdx.x;   // 640*512
  int n = idx >> 9;
  int f = idx & 511;
  const float w0 = 6.283185307179586f / 1024.f;
  float c = 0.f, s = 0.f;
  if (n <= 512) {
    int ph = (f * n) & 1023;
    float si, co;
    __sincosf((float)ph * w0, &si, &co);
    float wn = 0.5f - 0.5f * __cosf((float)n * w0);
    float sc = (f == 0) ? 1.f : 2.f;
    float b = sc * CQ * wn;
    c = co * b;
    s = si * b;
  }
  Bc[idx] = __float2bfloat16(c);
  Bs[idx] = __float2bfloat16(s);
  if (idx < NKER) {
    float v = 0.f;
    if (idx <= 512) {
      float wn2 = 0.5f - 0.5f * __cosf((float)idx * w0);
      v = ((idx & 1) ? -1.f : 1.f) * wn2 * CQ;
    }
    s_tab[idx] = v;
  }
}

// C^T[n][t] = sum_c ker[n][c] * x[b][c][t][ri], fused transpose+window epilogue.
// Block: 128 n  x 64 t, BK=32, dbuf, 64KB LDS. x staged raw fp32 (re,im pairs),
// converted to bf16 at fragment read. ker staged bf16 with slot-swizzle.
// frames0[m][n]=U-V+add, frames1[m][...mirror]=U+V+add; y==4 block: fr512 only.
__global__ __launch_bounds__(256, 2) void gemm_fused(
    const float* __restrict__ x,
    const __hip_bfloat16* __restrict__ kerc, const __hip_bfloat16* __restrict__ kers,
    const float* __restrict__ s_tab,
    __hip_bfloat16* __restrict__ frames0, __hip_bfloat16* __restrict__ frames1,
    float* __restrict__ fr512) {
  // buf layout (bf16 elems): x raw [0,8192) (16KB), kc [8192,12288), ks [12288,16384)
  __shared__ __align__(16) __hip_bfloat16 smem[32768];  // 64 KB total (2 bufs)
  int tid = threadIdx.x;
  int lane = tid & 63;
  int wv = tid >> 6;
  int wn_ = (wv >> 1) * 64;        // wave n-offset within 128
  int wt_ = (wv & 1) * 32;         // wave t-offset within 64

  // decode block: XCD co-location: 5 y-blocks of one t-slice land on same XCD
  int w = blockIdx.x;              // 0..1279
  int g8 = w >> 3;
  int y = g8 % 5;                  // n-tile 0..4 (4 => Nyquist rows 512..639)
  int tb = (w & 7) + 8 * (g8 / 5); // 0..255
  int b = tb >> 4;
  int t0 = (tb & 15) * 64;
  int N0 = y * 128;
  size_t bO = (size_t)b * 513;

  f32x4 aU[4][2] = {};
  f32x4 aV[4][2] = {};

#define STAGE(KT, BB)                                                              \
  {                                                                                \
    int k0 = (KT) * 32;                                                            \
    int base = (BB) * 16384;                                                       \
    _Pragma("unroll")                                                              \
    for (int i = 0; i < 4; ++i) {                                                  \
      int c = i * 8 + (tid >> 5);                                                  \
      int tch = tid & 31;                                                          \
      gload_lds16(x + ((bO + k0 + c) * 1024 + t0 + tch * 2) * 2,                   \
                  &smem[base + i * 2048 + tid * 8]);                               \
    }                                                                              \
    _Pragma("unroll")                                                              \
    for (int p = 0; p < 2; ++p) {                                                  \
      int row = p * 64 + (tid >> 2);                                               \
      int ksl = ((tid & 3) ^ ((row >> 1) & 3)) * 8;                                \
      gload_lds16(kerc + (size_t)(N0 + row) * 512 + k0 + ksl,                      \
                  &smem[base + 8192 + p * 2048 + tid * 8]);                        \
      gload_lds16(kers + (size_t)(N0 + row) * 512 + k0 + ksl,                      \
                  &smem[base + 12288 + p * 2048 + tid * 8]);                       \
    }                                                                              \
  }

  STAGE(0, 0);
  __syncthreads();

  for (int kt = 0; kt < 16; ++kt) {
    int cur = (kt & 1) * 16384;
    if (kt + 1 < 16) STAGE(kt + 1, (kt & 1) ^ 1);

    const char* xb = (const char*)(smem + cur);
    const __hip_bfloat16* kc = smem + cur + 8192;
    const __hip_bfloat16* ks2 = smem + cur + 12288;

    bf16x8 afc[4], afs[4];
#pragma unroll
    for (int ni = 0; ni < 4; ++ni) {
      int row = wn_ + ni * 16 + (lane & 15);
      int sl = ((lane >> 4) ^ ((row >> 1) & 3)) * 8;
      afc[ni] = *(const bf16x8*)&kc[row * 32 + sl];
      afs[ni] = *(const bf16x8*)&ks2[row * 32 + sl];
    }
#pragma unroll
    for (int ti = 0; ti < 2; ++ti) {
      int tl = wt_ + ti * 16 + (lane & 15);
      int sbase = (lane >> 4) * 8;
      bf16x8 xr, xi;
#pragma unroll
      for (int j = 0; j < 8; ++j) {
        float2 v = *(const float2*)(xb + (sbase + j) * 512 + tl * 8);
        xr[j] = (__bf16)v.x;
        xi[j] = (__bf16)v.y;
      }
#pragma unroll
      for (int ni = 0; ni < 4; ++ni)
        aU[ni][ti] = __builtin_amdgcn_mfma_f32_16x16x32_bf16(
            afc[ni], xr, aU[ni][ti], 0, 0, 0);
#pragma unroll
      for (int ni = 0; ni < 4; ++ni)
        aV[ni][ti] = __builtin_amdgcn_mfma_f32_16x16x32_bf16(
            afs[ni], xi, aV[ni][ti], 0, 0, 0);
    }
    __syncthreads();
  }

  // rank-1 f=512 term inputs
  float sn[4][4];
#pragma unroll
  for (int ni = 0; ni < 4; ++ni)
#pragma unroll
    for (int r = 0; r < 4; ++r)
      sn[ni][r] = s_tab[N0 + wn_ + ni * 16 + (lane >> 4) * 4 + r];
  float rv[2];
#pragma unroll
  for (int ti = 0; ti < 2; ++ti)
    rv[ti] = x[((bO + 512) * 1024 + t0 + wt_ + ti * 16 + (lane & 15)) * 2];

  if (y == 4) {
    // only n-row 512 matters: nl==0 -> wn_==0, lane>>4==0, r==0
    if (wn_ == 0 && (lane >> 4) == 0) {
#pragma unroll
      for (int ti = 0; ti < 2; ++ti) {
        int tl = wt_ + ti * 16 + (lane & 15);
        fr512[(size_t)b * 1024 + t0 + tl] =
            aU[0][ti][0] - aV[0][ti][0] + rv[ti] * sn[0][0];
      }
    }
    return;
  }

  // epilogue: fragments -> LDS (granule-swizzled) -> coalesced bf16 stores
  __hip_bfloat16* fr0 = smem;          // [64 t][128 n]
  __hip_bfloat16* fr1 = smem + 8192;
#pragma unroll
  for (int ni = 0; ni < 4; ++ni) {
#pragma unroll
    for (int r = 0; r < 4; ++r) {
      int nl = wn_ + ni * 16 + (lane >> 4) * 4 + r;
      int c2 = 127 - nl;
#pragma unroll
      for (int ti = 0; ti < 2; ++ti) {
        int tl = wt_ + ti * 16 + (lane & 15);
        int tx = (tl & 7) << 3;
        float add = rv[ti] * sn[ni][r];
        float U = aU[ni][ti][r], V = aV[ni][ti][r];
        fr0[tl * 128 + ((nl & ~7) ^ tx) + (nl & 7)] = __float2bfloat16(U - V + add);
        fr1[tl * 128 + ((c2 & ~7) ^ tx) + (c2 & 7)] = __float2bfloat16(U + V + add);
      }
    }
  }
  __syncthreads();
  int row = tid >> 2;                  // 0..63 (t-local)
  int g0 = (tid & 3) * 4;              // first granule (8 elems) of this quarter-row
  size_t m = (size_t)b * 1024 + t0 + row;
  const int4* s0 = (const int4*)fr0;
  const int4* s1 = (const int4*)fr1;
  int4* d0 = (int4*)(frames0 + m * 512 + N0 + g0 * 8);
  int4* d1 = (int4*)(frames1 + m * 512 + (384 - N0) + g0 * 8);
#pragma unroll
  for (int c = 0; c < 4; ++c) {
    int q = (g0 + c) ^ (row & 7);
    d0[c] = s0[row * 16 + q];
    d1[c] = s1[row * 16 + q];
  }
}

// out[b][l] = sum_t frame[t][l-256t]; j<512 -> frames0[m][j], j==512 -> fr512[m],
// j>512 -> frames1[m][j-513]
__global__ void ola(const __hip_bfloat16* __restrict__ frames0,
                    const __hip_bfloat16* __restrict__ frames1,
                    const float* __restrict__ fr512, float* __restrict__ out, int total) {
  int idx = blockIdx.x * blockDim.x + threadIdx.x;
  int stride = gridDim.x * blockDim.x;
  for (; idx < total; idx += stride) {
    int b = idx / LOUT;
    int l = idx - b * LOUT;
    int thi = l >> 8; if (thi > NT - 1) thi = NT - 1;
    int tlo = (l - 768) >> 8; if (tlo < 0) tlo = 0;
    float s = 0.f;
    for (int t = tlo; t <= thi; ++t) {
      int j = l - (t << 8);
      size_t m = (size_t)b * NT + t;
      if (j < 512) s += __bfloat162float(frames0[m * 512 + j]);
      else if (j > 512) s += __bfloat162float(frames1[m * 512 + (j - 513)]);
      else s += fr512[m];
    }
    out[idx] = s;
  }
}

extern "C" void kernel_launch(void* const* d_in, const int* in_sizes, int n_in,
                              void* d_out, int out_size, void* d_ws, size_t ws_size,
                              hipStream_t stream) {
  (void)in_sizes; (void)n_in; (void)out_size; (void)ws_size;
  const float* x = (const float*)d_in[0];
  float* out = (float*)d_out;
  char* ws = (char*)d_ws;
  size_t oBc = 0;
  size_t oBs = oBc + (size_t)NKER * 512 * 2;     // 640 KB
  size_t oS  = oBs + (size_t)NKER * 512 * 2;     // 640 KB
  size_t oF5 = oS + NKER * 4;                    // 2.5 KB
  size_t oF0 = oF5 + (size_t)MM * 4;             // 64 KB
  size_t oF1 = oF0 + (size_t)MM * 512 * 2;       // 16.75 MB
  __hip_bfloat16* Bc = (__hip_bfloat16*)(ws + oBc);
  __hip_bfloat16* Bs = (__hip_bfloat16*)(ws + oBs);
  float* s_tab = (float*)(ws + oS);
  float* fr512 = (float*)(ws + oF5);
  __hip_bfloat16* frames0 = (__hip_bfloat16*)(ws + oF0);
  __hip_bfloat16* frames1 = (__hip_bfloat16*)(ws + oF1);

  build_B<<<dim3(NKER * 512 / 256), dim3(256), 0, stream>>>(Bc, Bs, s_tab);
  gemm_fused<<<dim3(1280), dim3(256), 0, stream>>>(x, Bc, Bs, s_tab,
                                                   frames0, frames1, fr512);
  ola<<<dim3(2048), dim3(256), 0, stream>>>(frames0, frames1, fr512, out, NB * LOUT);
}

// Round 9
// 87.256 us; speedup vs baseline: 1.1920x; 1.0356x over previous
//
#include <hip/hip_runtime.h>
#include <hip/hip_bf16.h>

#define HOP 256
#define NB 16
#define NT 1024
#define MM (NB*NT)                 // 16384
#define LOUT ((NT-1)*HOP + 1024)   // 262912
#define CQ (2.0f/(3.0f*1024.0f))   // (HOP/sum(win^2))/NFFT

typedef __bf16 bf16x8 __attribute__((ext_vector_type(8)));
typedef __bf16 bf16x4 __attribute__((ext_vector_type(4)));
typedef float f32x4 __attribute__((ext_vector_type(4)));

__device__ __forceinline__ void gload_lds16(const void* g, void* l) {
  __builtin_amdgcn_global_load_lds(
      (const __attribute__((address_space(1))) void*)g,
      (__attribute__((address_space(3))) void*)l, 16, 0, 0);
}

// B''[np][c], np,c in [0,1024): rows np<512 give U-V (frame[np]), rows np>=512 give
// U+V at n=np-512 (frame[1024-n]); c<512 = cos part, c>=512 = sin part (sign -/+).
// win[n] (symmetric) and CQ folded in. Row 512 is all-zero (win[0]=0) — junk column.
__global__ void build_B(__hip_bfloat16* __restrict__ Bp, float* __restrict__ s_tab) {
  int idx = blockIdx.x * 256 + threadIdx.x;   // 1024*1024 total
  int np = idx >> 10, c = idx & 1023;
  int n = np & 511, f = c & 511;
  const float w0 = 6.283185307179586f / 1024.f;
  int ph = (f * n) & 1023;
  float si, co;
  __sincosf((float)ph * w0, &si, &co);
  float wn = 0.5f - 0.5f * __cosf((float)n * w0);
  float sc = (f == 0) ? 1.f : 2.f;
  float b = sc * CQ * wn;
  float v = (c < 512) ? co * b : ((np < 512) ? -si * b : si * b);
  Bp[idx] = __float2bfloat16(v);
  if (idx < 512) {
    float wn2 = 0.5f - 0.5f * __cosf((float)idx * w0);
    s_tab[idx] = ((idx & 1) ? -1.f : 1.f) * wn2 * CQ;
  }
}

// A'[b*1024+t][c] : c<512 -> re x[b][c][t], c>=512 -> im x[b][c-512][t].
// re512[m] = x[b][512][t][0].
__global__ void pack_a(const float* __restrict__ x, __hip_bfloat16* __restrict__ A,
                       float* __restrict__ re512) {
  __shared__ float2 tile[64][65];
  int b = blockIdx.z, f0 = blockIdx.y * 64, t0 = blockIdx.x * 64;
  int tid = threadIdx.x, tl = tid & 63, th = tid >> 6;
#pragma unroll
  for (int r = 0; r < 16; ++r) {
    int fl = r * 4 + th;
    tile[fl][tl] = *(const float2*)(x + (((size_t)b * 513 + f0 + fl) * 1024 + (t0 + tl)) * 2);
  }
  __syncthreads();
  int row = tid >> 2;
#pragma unroll
  for (int i = 0; i < 4; ++i) {
    int chunk = (tid & 3) * 4 + i;
    float2 v0 = tile[chunk * 4 + 0][row], v1 = tile[chunk * 4 + 1][row];
    float2 v2 = tile[chunk * 4 + 2][row], v3 = tile[chunk * 4 + 3][row];
    bf16x4 pr, pi;
    pr[0] = (__bf16)v0.x; pr[1] = (__bf16)v1.x; pr[2] = (__bf16)v2.x; pr[3] = (__bf16)v3.x;
    pi[0] = (__bf16)v0.y; pi[1] = (__bf16)v1.y; pi[2] = (__bf16)v2.y; pi[3] = (__bf16)v3.y;
    size_t rowm = (size_t)(b * 1024 + t0 + row) * 1024 + f0 + chunk * 4;
    *(bf16x4*)(A + rowm) = pr;
    *(bf16x4*)(A + rowm + 512) = pi;
  }
  if (blockIdx.y == 0 && tid < 64)
    re512[b * 1024 + t0 + tid] = x[(((size_t)b * 513 + 512) * 1024 + t0 + tid) * 2];
}

// fr512[m] = CQ * (re0 + re512 + sum_{f=1..511} 2*(-1)^f re_f)
__global__ void nyq(const __hip_bfloat16* __restrict__ A, const float* __restrict__ re512,
                    float* __restrict__ fr512) {
  int tid = threadIdx.x, lane = tid & 63;
  int row = blockIdx.x * 4 + (tid >> 6);
  const bf16x8 v = *(const bf16x8*)&A[(size_t)row * 1024 + lane * 8];
  float s = 0.f;
#pragma unroll
  for (int e = 0; e < 8; ++e) {
    int f = lane * 8 + e;
    float w = (f == 0) ? 1.f : ((f & 1) ? -2.f : 2.f);
    s += w * (float)v[e];
  }
#pragma unroll
  for (int off = 32; off >= 1; off >>= 1) s += __shfl_xor(s, off, 64);
  if (lane == 0) fr512[row] = (s + re512[row]) * CQ;
}

// 256x256 tile, BK=64, 8 waves (2Mx4N), 8-phase counted-vmcnt schedule (T3+T4),
// st_16x32 LDS swizzle via pre-swizzled global source (col ^= ((row>>2)&1)<<4),
// per-phase setprio around MFMA cluster (T5), bijective XCD swizzle (T1).
// Epilogue adds rank-1 f=512 term and stores C straight (bf16) via LDS bounce.
__global__ __launch_bounds__(512, 1) void gemm8(
    const __hip_bfloat16* __restrict__ A, const __hip_bfloat16* __restrict__ Bp,
    const float* __restrict__ re512, const float* __restrict__ s_tab,
    __hip_bfloat16* __restrict__ C) {
  __shared__ __align__(16) __hip_bfloat16 smem[65536];  // 128 KB
  int tid = threadIdx.x, lane = tid & 63, wv = tid >> 6;
  int wr = wv >> 2, wc = wv & 3;
  int nf = (blockIdx.x & 7) * 32 + (blockIdx.x >> 3);   // XCD swizzle, 256%8==0
  int M0 = (nf & 63) * 256, N0 = (nf >> 6) * 256;

  __hip_bfloat16* sA0 = smem;
  __hip_bfloat16* sA1 = smem + 16384;
  __hip_bfloat16* sB0 = smem + 32768;
  __hip_bfloat16* sB1 = smem + 49152;

  f32x4 acc[8][4] = {};
  const int srow = tid >> 3, sc8 = (tid & 7) * 8;

  // stage one 64-row granule (1 load/thread), linear LDS dest + pre-swizzled source
#define SG(X, R0, KT, G, LB)                                                   \
  {                                                                            \
    int r_ = (G) * 64 + srow;                                                  \
    int cs_ = sc8 ^ (((r_ >> 2) & 1) << 4);                                    \
    gload_lds16((X) + (size_t)((R0) + r_) * 1024 + (KT) * 64 + cs_,            \
                (LB) + (G) * 4096 + tid * 8);                                  \
  }
#define VMCNT(N) asm volatile("s_waitcnt vmcnt(" #N ")" ::: "memory")
#define BAR() __builtin_amdgcn_s_barrier()

#define LOADA(Q)                                                               \
  _Pragma("unroll") for (int j = 0; j < 2; ++j) {                              \
    int row = wr * 128 + (2 * (Q) + j) * 16 + (lane & 15);                     \
    int sw = ((row >> 2) & 1) << 4;                                            \
    _Pragma("unroll") for (int ks = 0; ks < 2; ++ks)                           \
        af[j][ks] = *(const bf16x8*)&cA[row * 64 +                             \
                                        ((ks * 32 + (lane >> 4) * 8) ^ sw)];   \
  }
#define MFMAQ(Q)                                                               \
  __builtin_amdgcn_s_setprio(1);                                               \
  _Pragma("unroll") for (int j = 0; j < 2; ++j)                                \
  _Pragma("unroll") for (int ks = 0; ks < 2; ++ks)                             \
  _Pragma("unroll") for (int ni = 0; ni < 4; ++ni)                             \
      acc[2 * (Q) + j][ni] = __builtin_amdgcn_mfma_f32_16x16x32_bf16(          \
          af[j][ks], bfr[ks][ni], acc[2 * (Q) + j][ni], 0, 0, 0);              \
  __builtin_amdgcn_s_setprio(0);

  // prologue: tile 0 -> buf0 (order: B g0..g3, A g0,g2 then g1,g3)
  SG(Bp, N0, 0, 0, sB0); SG(Bp, N0, 0, 1, sB0);
  SG(Bp, N0, 0, 2, sB0); SG(Bp, N0, 0, 3, sB0);
  SG(A, M0, 0, 0, sA0);  SG(A, M0, 0, 2, sA0);
  SG(A, M0, 0, 1, sA0);  SG(A, M0, 0, 3, sA0);
  VMCNT(2);   // B g0..3 + A g0,g2 landed; A g1,g3 still in flight
  BAR();

  for (int t = 0; t < 16; ++t) {
    __hip_bfloat16* cA = (t & 1) ? sA1 : sA0;
    __hip_bfloat16* cB = (t & 1) ? sB1 : sB0;
    __hip_bfloat16* nA = (t & 1) ? sA0 : sA1;
    __hip_bfloat16* nB = (t & 1) ? sB0 : sB1;
    int k1 = t + 1;
    bf16x8 bfr[2][4], af[2][2];

    // ---- phase 0: B-frags (whole tile) + A mi0,1; stage next B g0,g1
#pragma unroll
    for (int ni = 0; ni < 4; ++ni) {
      int row = wc * 64 + ni * 16 + (lane & 15);
      int sw = ((row >> 2) & 1) << 4;
#pragma unroll
      for (int ks = 0; ks < 2; ++ks)
        bfr[ks][ni] = *(const bf16x8*)&cB[row * 64 + ((ks * 32 + (lane >> 4) * 8) ^ sw)];
    }
    LOADA(0);
    if (t < 15) { SG(Bp, N0, k1, 0, nB); SG(Bp, N0, k1, 1, nB); }
    BAR();
    MFMAQ(0);
    BAR();
    // ---- phase 1: A mi2,3; stage next B g2,g3; mid-tile wait for own A g1,g3
    LOADA(1);
    if (t < 15) { SG(Bp, N0, k1, 2, nB); SG(Bp, N0, k1, 3, nB); }
    BAR();
    MFMAQ(1);
    if (t < 15) { VMCNT(4); } else { VMCNT(0); }
    BAR();
    // ---- phase 2: A mi4,5; stage next A g0,g2
    LOADA(2);
    if (t < 15) { SG(A, M0, k1, 0, nA); SG(A, M0, k1, 2, nA); }
    BAR();
    MFMAQ(2);
    BAR();
    // ---- phase 3: A mi6,7; stage next A g1,g3; boundary wait
    LOADA(3);
    if (t < 15) { SG(A, M0, k1, 1, nA); SG(A, M0, k1, 3, nA); }
    BAR();
    MFMAQ(3);
    if (t < 15) { VMCNT(2); }
    BAR();
  }

  // epilogue: add rank-1 term, bounce through LDS, coalesced bf16 stores
  __hip_bfloat16* ct = smem;
  float snv[4];
#pragma unroll
  for (int ni = 0; ni < 4; ++ni)
    snv[ni] = s_tab[(N0 + wc * 64 + ni * 16 + (lane & 15)) & 511];
#pragma unroll
  for (int mi = 0; mi < 8; ++mi) {
    int rbase = wr * 128 + mi * 16 + (lane >> 4) * 4;
    float4 rv = *(const float4*)&re512[M0 + rbase];
#pragma unroll
    for (int ni = 0; ni < 4; ++ni) {
      int col = wc * 64 + ni * 16 + (lane & 15);
#pragma unroll
      for (int r = 0; r < 4; ++r) {
        float val = acc[mi][ni][r] + ((const float*)&rv)[r] * snv[ni];
        ct[(rbase + r) * 256 + col] = __float2bfloat16(val);
      }
    }
  }
  BAR();
#pragma unroll
  for (int k = 0; k < 16; ++k) {
    int row = k * 16 + (tid >> 5);
    int c0 = (tid & 31) * 8;
    *(int4*)(C + (size_t)(M0 + row) * 1024 + N0 + c0) = *(const int4*)&ct[row * 256 + c0];
  }
#undef SG
#undef VMCNT
#undef BAR
#undef LOADA
#undef MFMAQ
}

// out[b][l] = sum_t frame[t][l-256t]; frame[j]: j<512 -> C[m][j], j==512 -> fr512[m],
// j>512 -> C[m][1536-j]
__global__ void ola(const __hip_bfloat16* __restrict__ C, const float* __restrict__ fr512,
                    float* __restrict__ out, int total) {
  int idx = blockIdx.x * blockDim.x + threadIdx.x;
  int stride = gridDim.x * blockDim.x;
  for (; idx < total; idx += stride) {
    int b = idx / LOUT;
    int l = idx - b * LOUT;
    int thi = l >> 8; if (thi > NT - 1) thi = NT - 1;
    int tlo = (l - 768) >> 8; if (tlo < 0) tlo = 0;
    float s = 0.f;
    for (int t = tlo; t <= thi; ++t) {
      int j = l - (t << 8);
      size_t m = (size_t)b * NT + t;
      if (j < 512) s += __bfloat162float(C[m * 1024 + j]);
      else if (j > 512) s += __bfloat162float(C[m * 1024 + 1536 - j]);
      else s += fr512[m];
    }
    out[idx] = s;
  }
}

extern "C" void kernel_launch(void* const* d_in, const int* in_sizes, int n_in,
                              void* d_out, int out_size, void* d_ws, size_t ws_size,
                              hipStream_t stream) {
  (void)in_sizes; (void)n_in; (void)out_size; (void)ws_size;
  const float* x = (const float*)d_in[0];
  float* out = (float*)d_out;
  char* ws = (char*)d_ws;
  size_t oA  = 0;
  size_t oB  = oA + (size_t)MM * 1024 * 2;         // 33.55 MB
  size_t oS  = oB + (size_t)1024 * 1024 * 2;       // +2 MB
  size_t oR5 = oS + 512 * 4;
  size_t oF5 = oR5 + (size_t)MM * 4;
  size_t oC  = oF5 + (size_t)MM * 4;
  __hip_bfloat16* A  = (__hip_bfloat16*)(ws + oA);
  __hip_bfloat16* Bp = (__hip_bfloat16*)(ws + oB);
  float* s_tab = (float*)(ws + oS);
  float* re512 = (float*)(ws + oR5);
  float* fr512 = (float*)(ws + oF5);
  __hip_bfloat16* C  = (__hip_bfloat16*)(ws + oC);

  build_B<<<dim3(1024 * 1024 / 256), dim3(256), 0, stream>>>(Bp, s_tab);
  pack_a<<<dim3(16, 8, 16), dim3(256), 0, stream>>>(x, A, re512);
  nyq<<<dim3(MM / 4), dim3(256), 0, stream>>>(A, re512, fr512);
  gemm8<<<dim3(256), dim3(512), 0, stream>>>(A, Bp, re512, s_tab, C);
  ola<<<dim3(2048), dim3(256), 0, stream>>>(C, fr512, out, NB * LOUT);
}

// Round 10
// 85.093 us; speedup vs baseline: 1.2223x; 1.0254x over previous
//
#include <hip/hip_runtime.h>
#include <hip/hip_bf16.h>

#define HOP 256
#define NB 16
#define NT 1024
#define MM (NB*NT)                 // 16384
#define LOUT ((NT-1)*HOP + 1024)   // 262912
#define CQ (2.0f/(3.0f*1024.0f))   // (HOP/sum(win^2))/NFFT

typedef __bf16 bf16x8 __attribute__((ext_vector_type(8)));
typedef __bf16 bf16x4 __attribute__((ext_vector_type(4)));
typedef float f32x4 __attribute__((ext_vector_type(4)));

__device__ __forceinline__ void gload_lds16(const void* g, void* l) {
  __builtin_amdgcn_global_load_lds(
      (const __attribute__((address_space(1))) void*)g,
      (__attribute__((address_space(3))) void*)l, 16, 0, 0);
}

// B''[np][c], np,c in [0,1024): rows np<512 give U-V (frame[np]), rows np>=512 give
// U+V at n=np-512 (frame[1024-n]); c<512 = cos part, c>=512 = sin part (sign -/+).
// win[n] (symmetric) and CQ folded in.
__global__ void build_B(__hip_bfloat16* __restrict__ Bp, float* __restrict__ s_tab) {
  int idx = blockIdx.x * 256 + threadIdx.x;   // 1024*1024 total
  int np = idx >> 10, c = idx & 1023;
  int n = np & 511, f = c & 511;
  const float w0 = 6.283185307179586f / 1024.f;
  int ph = (f * n) & 1023;
  float si, co;
  __sincosf((float)ph * w0, &si, &co);
  float wn = 0.5f - 0.5f * __cosf((float)n * w0);
  float sc = (f == 0) ? 1.f : 2.f;
  float b = sc * CQ * wn;
  float v = (c < 512) ? co * b : ((np < 512) ? -si * b : si * b);
  Bp[idx] = __float2bfloat16(v);
  if (idx < 512) {
    float wn2 = 0.5f - 0.5f * __cosf((float)idx * w0);
    s_tab[idx] = ((idx & 1) ? -1.f : 1.f) * wn2 * CQ;
  }
}

// A'[b*1024+t][c] : c<512 -> re x[b][c][t], c>=512 -> im x[b][c-512][t].
// re512[m] = x[b][512][t][0]. Also accumulates Nyquist partials into fr512a:
// fr512a[m] += sum_{f in block} w(f)*re_f  (+ re512 from the y==0 block),
// w(0)=1, w(f)=2*(-1)^f. frame[512] = fr512a*CQ (win[512]=1).
__global__ void pack_a(const float* __restrict__ x, __hip_bfloat16* __restrict__ A,
                       float* __restrict__ re512, float* __restrict__ fr512a) {
  __shared__ float2 tile[64][65];
  __shared__ float red[4][64];
  int b = blockIdx.z, f0 = blockIdx.y * 64, t0 = blockIdx.x * 64;
  int tid = threadIdx.x, tl = tid & 63, th = tid >> 6;
#pragma unroll
  for (int r = 0; r < 16; ++r) {
    int fl = r * 4 + th;
    tile[fl][tl] = *(const float2*)(x + (((size_t)b * 513 + f0 + fl) * 1024 + (t0 + tl)) * 2);
  }
  __syncthreads();
  int row = tid >> 2;
#pragma unroll
  for (int i = 0; i < 4; ++i) {
    int chunk = (tid & 3) * 4 + i;
    float2 v0 = tile[chunk * 4 + 0][row], v1 = tile[chunk * 4 + 1][row];
    float2 v2 = tile[chunk * 4 + 2][row], v3 = tile[chunk * 4 + 3][row];
    bf16x4 pr, pi;
    pr[0] = (__bf16)v0.x; pr[1] = (__bf16)v1.x; pr[2] = (__bf16)v2.x; pr[3] = (__bf16)v3.x;
    pi[0] = (__bf16)v0.y; pi[1] = (__bf16)v1.y; pi[2] = (__bf16)v2.y; pi[3] = (__bf16)v3.y;
    size_t rowm = (size_t)(b * 1024 + t0 + row) * 1024 + f0 + chunk * 4;
    *(bf16x4*)(A + rowm) = pr;
    *(bf16x4*)(A + rowm + 512) = pi;
  }
  // Nyquist partial over this block's 64 freqs for each of 64 t's
  float p = 0.f;
#pragma unroll
  for (int i = 0; i < 16; ++i) {
    int fl = th * 16 + i;
    int f = f0 + fl;
    float w = (f == 0) ? 1.f : ((f & 1) ? -2.f : 2.f);
    p += w * tile[fl][tl].x;
  }
  red[th][tl] = p;
  __syncthreads();
  if (tid < 64) {
    float s4 = red[0][tid] + red[1][tid] + red[2][tid] + red[3][tid];
    if (blockIdx.y == 0) {
      float rv = x[(((size_t)b * 513 + 512) * 1024 + t0 + tid) * 2];
      re512[b * 1024 + t0 + tid] = rv;
      s4 += rv;
    }
    atomicAdd(&fr512a[b * 1024 + t0 + tid], s4);
  }
}

// 256x256 tile, BK=64, 8 waves (2Mx4N), 8-phase counted-vmcnt schedule (T3+T4),
// full 3-bit slot swizzle: LDS[row][slot] = G[row][slot ^ (row&7)] (16B slots),
// applied via pre-swizzled global source (rule 21); fragment reads XOR the same.
// setprio around MFMA clusters (T5), XCD swizzle (T1). Epilogue adds rank-1
// f=512 term and stores C (bf16) via LDS bounce.
__global__ __launch_bounds__(512, 1) void gemm8(
    const __hip_bfloat16* __restrict__ A, const __hip_bfloat16* __restrict__ Bp,
    const float* __restrict__ re512, const float* __restrict__ s_tab,
    __hip_bfloat16* __restrict__ C) {
  __shared__ __align__(16) __hip_bfloat16 smem[65536];  // 128 KB
  int tid = threadIdx.x, lane = tid & 63, wv = tid >> 6;
  int wr = wv >> 2, wc = wv & 3;
  int nf = (blockIdx.x & 7) * 32 + (blockIdx.x >> 3);   // XCD swizzle, 256%8==0
  int M0 = (nf & 63) * 256, N0 = (nf >> 6) * 256;

  __hip_bfloat16* sA0 = smem;
  __hip_bfloat16* sA1 = smem + 16384;
  __hip_bfloat16* sB0 = smem + 32768;
  __hip_bfloat16* sB1 = smem + 49152;

  f32x4 acc[8][4] = {};

  // stage one 64-row granule (1 load/thread): linear LDS dest (row=tid>>3,
  // slot=tid&7), source slot pre-XOR'd with row&7.
#define SG(X, R0, KT, G, LB)                                                   \
  {                                                                            \
    int r_ = (G) * 64 + (tid >> 3);                                            \
    int s_ = (((tid & 7) ^ (r_ & 7)) * 8);                                     \
    gload_lds16((X) + (size_t)((R0) + r_) * 1024 + (KT) * 64 + s_,             \
                (LB) + (G) * 4096 + tid * 8);                                  \
  }
#define VMCNT(N) asm volatile("s_waitcnt vmcnt(" #N ")" ::: "memory")
#define BAR() __builtin_amdgcn_s_barrier()

#define LOADA(Q)                                                               \
  _Pragma("unroll") for (int j = 0; j < 2; ++j) {                              \
    int row = wr * 128 + (2 * (Q) + j) * 16 + (lane & 15);                     \
    _Pragma("unroll") for (int ks = 0; ks < 2; ++ks)                           \
        af[j][ks] = *(const bf16x8*)&cA[row * 64 +                             \
            (((ks * 4 + (lane >> 4)) ^ (row & 7)) * 8)];                       \
  }
#define MFMAQ(Q)                                                               \
  __builtin_amdgcn_s_setprio(1);                                               \
  _Pragma("unroll") for (int j = 0; j < 2; ++j)                                \
  _Pragma("unroll") for (int ks = 0; ks < 2; ++ks)                             \
  _Pragma("unroll") for (int ni = 0; ni < 4; ++ni)                             \
      acc[2 * (Q) + j][ni] = __builtin_amdgcn_mfma_f32_16x16x32_bf16(          \
          af[j][ks], bfr[ks][ni], acc[2 * (Q) + j][ni], 0, 0, 0);              \
  __builtin_amdgcn_s_setprio(0);

  // prologue: tile 0 -> buf0 (order: B g0..g3, A g0,g2 then g1,g3)
  SG(Bp, N0, 0, 0, sB0); SG(Bp, N0, 0, 1, sB0);
  SG(Bp, N0, 0, 2, sB0); SG(Bp, N0, 0, 3, sB0);
  SG(A, M0, 0, 0, sA0);  SG(A, M0, 0, 2, sA0);
  SG(A, M0, 0, 1, sA0);  SG(A, M0, 0, 3, sA0);
  VMCNT(2);   // B g0..3 + A g0,g2 landed; A g1,g3 still in flight
  BAR();

  for (int t = 0; t < 16; ++t) {
    __hip_bfloat16* cA = (t & 1) ? sA1 : sA0;
    __hip_bfloat16* cB = (t & 1) ? sB1 : sB0;
    __hip_bfloat16* nA = (t & 1) ? sA0 : sA1;
    __hip_bfloat16* nB = (t & 1) ? sB0 : sB1;
    int k1 = t + 1;
    bf16x8 bfr[2][4], af[2][2];

    // ---- phase 0: B-frags (whole tile) + A mi0,1; stage next B g0,g1
#pragma unroll
    for (int ni = 0; ni < 4; ++ni) {
      int row = wc * 64 + ni * 16 + (lane & 15);
#pragma unroll
      for (int ks = 0; ks < 2; ++ks)
        bfr[ks][ni] = *(const bf16x8*)&cB[row * 64 +
            (((ks * 4 + (lane >> 4)) ^ (row & 7)) * 8)];
    }
    LOADA(0);
    if (t < 15) { SG(Bp, N0, k1, 0, nB); SG(Bp, N0, k1, 1, nB); }
    BAR();
    MFMAQ(0);
    BAR();
    // ---- phase 1: A mi2,3; stage next B g2,g3; mid-tile wait for own A g1,g3
    LOADA(1);
    if (t < 15) { SG(Bp, N0, k1, 2, nB); SG(Bp, N0, k1, 3, nB); }
    BAR();
    MFMAQ(1);
    if (t < 15) { VMCNT(4); } else { VMCNT(0); }
    BAR();
    // ---- phase 2: A mi4,5; stage next A g0,g2
    LOADA(2);
    if (t < 15) { SG(A, M0, k1, 0, nA); SG(A, M0, k1, 2, nA); }
    BAR();
    MFMAQ(2);
    BAR();
    // ---- phase 3: A mi6,7; stage next A g1,g3; boundary wait
    LOADA(3);
    if (t < 15) { SG(A, M0, k1, 1, nA); SG(A, M0, k1, 3, nA); }
    BAR();
    MFMAQ(3);
    if (t < 15) { VMCNT(2); }
    BAR();
  }

  // epilogue: add rank-1 term, bounce through LDS, coalesced bf16 stores
  __hip_bfloat16* ct = smem;
  float snv[4];
#pragma unroll
  for (int ni = 0; ni < 4; ++ni)
    snv[ni] = s_tab[(N0 + wc * 64 + ni * 16 + (lane & 15)) & 511];
#pragma unroll
  for (int mi = 0; mi < 8; ++mi) {
    int rbase = wr * 128 + mi * 16 + (lane >> 4) * 4;
    float4 rv = *(const float4*)&re512[M0 + rbase];
#pragma unroll
    for (int ni = 0; ni < 4; ++ni) {
      int col = wc * 64 + ni * 16 + (lane & 15);
#pragma unroll
      for (int r = 0; r < 4; ++r) {
        float val = acc[mi][ni][r] + ((const float*)&rv)[r] * snv[ni];
        ct[(rbase + r) * 256 + col] = __float2bfloat16(val);
      }
    }
  }
  BAR();
#pragma unroll
  for (int k = 0; k < 16; ++k) {
    int row = k * 16 + (tid >> 5);
    int c0 = (tid & 31) * 8;
    *(int4*)(C + (size_t)(M0 + row) * 1024 + N0 + c0) = *(const int4*)&ct[row * 256 + c0];
  }
#undef SG
#undef VMCNT
#undef BAR
#undef LOADA
#undef MFMAQ
}

// out[b][l] = sum_t frame[t][l-256t]; frame[j]: j<512 -> C[m][j], j==512 ->
// fr512a[m]*CQ, j>512 -> C[m][1536-j]
__global__ void ola(const __hip_bfloat16* __restrict__ C, const float* __restrict__ fr512a,
                    float* __restrict__ out, int total) {
  int idx = blockIdx.x * blockDim.x + threadIdx.x;
  int stride = gridDim.x * blockDim.x;
  for (; idx < total; idx += stride) {
    int b = idx / LOUT;
    int l = idx - b * LOUT;
    int thi = l >> 8; if (thi > NT - 1) thi = NT - 1;
    int tlo = (l - 768) >> 8; if (tlo < 0) tlo = 0;
    float s = 0.f;
    for (int t = tlo; t <= thi; ++t) {
      int j = l - (t << 8);
      size_t m = (size_t)b * NT + t;
      if (j < 512) s += __bfloat162float(C[m * 1024 + j]);
      else if (j > 512) s += __bfloat162float(C[m * 1024 + 1536 - j]);
      else s += fr512a[m] * CQ;
    }
    out[idx] = s;
  }
}

extern "C" void kernel_launch(void* const* d_in, const int* in_sizes, int n_in,
                              void* d_out, int out_size, void* d_ws, size_t ws_size,
                              hipStream_t stream) {
  (void)in_sizes; (void)n_in; (void)out_size; (void)ws_size;
  const float* x = (const float*)d_in[0];
  float* out = (float*)d_out;
  char* ws = (char*)d_ws;
  size_t oA  = 0;
  size_t oB  = oA + (size_t)MM * 1024 * 2;         // 33.55 MB
  size_t oS  = oB + (size_t)1024 * 1024 * 2;       // +2 MB
  size_t oR5 = oS + 512 * 4;
  size_t oF5 = oR5 + (size_t)MM * 4;
  size_t oC  = oF5 + (size_t)MM * 4;
  __hip_bfloat16* A  = (__hip_bfloat16*)(ws + oA);
  __hip_bfloat16* Bp = (__hip_bfloat16*)(ws + oB);
  float* s_tab = (float*)(ws + oS);
  float* re512 = (float*)(ws + oR5);
  float* fr512a = (float*)(ws + oF5);
  __hip_bfloat16* C  = (__hip_bfloat16*)(ws + oC);

  hipMemsetAsync(fr512a, 0, (size_t)MM * 4, stream);
  build_B<<<dim3(1024 * 1024 / 256), dim3(256), 0, stream>>>(Bp, s_tab);
  pack_a<<<dim3(16, 8, 16), dim3(256), 0, stream>>>(x, A, re512, fr512a);
  gemm8<<<dim3(256), dim3(512), 0, stream>>>(A, Bp, re512, s_tab, C);
  ola<<<dim3(2048), dim3(256), 0, stream>>>(C, fr512a, out, NB * LOUT);
}

// Round 11
// 77.685 us; speedup vs baseline: 1.3389x; 1.0954x over previous
//
#include <hip/hip_runtime.h>
#include <hip/hip_bf16.h>

#define HOP 256
#define NB 16
#define NT 1024
#define MM (NB*NT)                 // 16384
#define LOUT ((NT-1)*HOP + 1024)   // 262912
#define CQ (2.0f/(3.0f*1024.0f))   // (HOP/sum(win^2))/NFFT
#define PACK_BLOCKS 2048           // 16 b x 8 f-tiles x 16 t-tiles

typedef __bf16 bf16x8 __attribute__((ext_vector_type(8)));
typedef __bf16 bf16x4 __attribute__((ext_vector_type(4)));
typedef float f32x4 __attribute__((ext_vector_type(4)));

__device__ __forceinline__ void gload_lds16(const void* g, void* l) {
  __builtin_amdgcn_global_load_lds(
      (const __attribute__((address_space(1))) void*)g,
      (__attribute__((address_space(3))) void*)l, 16, 0, 0);
}

// Fused prep: blocks [0,PACK_BLOCKS) pack x -> A' (bf16) + re512 + Nyquist slice
// partials; blocks [PACK_BLOCKS, +4096) build B'' + s_tab.
// A'[b*1024+t][c]: c<512 -> re x[b][c][t], c>=512 -> im x[b][c-512][t].
// slices[fy][m] = sum_{f in [64fy,64fy+64)} w(f)*re_f (+re512 when fy==0),
//   w(0)=1, w(f)=2*(-1)^f; frame[512] = (sum_fy slices)*CQ.
// B''[np][c]: rows np<512 -> U-V (frame[np]), np>=512 -> U+V at n=np-512
//   (frame[1024-n]); c<512 cos part, c>=512 sin part (sign -/+); win,CQ folded.
__global__ void prep(const float* __restrict__ x, __hip_bfloat16* __restrict__ A,
                     float* __restrict__ re512, float* __restrict__ slices,
                     __hip_bfloat16* __restrict__ Bp, float* __restrict__ s_tab) {
  int tid = threadIdx.x;
  if (blockIdx.x >= PACK_BLOCKS) {
    int idx = (blockIdx.x - PACK_BLOCKS) * 256 + tid;   // [0, 1024*1024)
    int np = idx >> 10, c = idx & 1023;
    int n = np & 511, f = c & 511;
    const float w0 = 6.283185307179586f / 1024.f;
    int ph = (f * n) & 1023;
    float si, co;
    __sincosf((float)ph * w0, &si, &co);
    float wn = 0.5f - 0.5f * __cosf((float)n * w0);
    float sc = (f == 0) ? 1.f : 2.f;
    float b = sc * CQ * wn;
    float v = (c < 512) ? co * b : ((np < 512) ? -si * b : si * b);
    Bp[idx] = __float2bfloat16(v);
    if (idx < 512) {
      float wn2 = 0.5f - 0.5f * __cosf((float)idx * w0);
      s_tab[idx] = ((idx & 1) ? -1.f : 1.f) * wn2 * CQ;
    }
    return;
  }
  __shared__ float2 tile[64][65];
  __shared__ float red[4][64];
  int w = blockIdx.x;
  int b = w >> 7, fy = (w >> 4) & 7, tx = w & 15;
  int f0 = fy * 64, t0 = tx * 64;
  int tl = tid & 63, th = tid >> 6;
#pragma unroll
  for (int r = 0; r < 16; ++r) {
    int fl = r * 4 + th;
    tile[fl][tl] = *(const float2*)(x + (((size_t)b * 513 + f0 + fl) * 1024 + (t0 + tl)) * 2);
  }
  __syncthreads();
  int row = tid >> 2;
#pragma unroll
  for (int i = 0; i < 4; ++i) {
    int chunk = (tid & 3) * 4 + i;
    float2 v0 = tile[chunk * 4 + 0][row], v1 = tile[chunk * 4 + 1][row];
    float2 v2 = tile[chunk * 4 + 2][row], v3 = tile[chunk * 4 + 3][row];
    bf16x4 pr, pi;
    pr[0] = (__bf16)v0.x; pr[1] = (__bf16)v1.x; pr[2] = (__bf16)v2.x; pr[3] = (__bf16)v3.x;
    pi[0] = (__bf16)v0.y; pi[1] = (__bf16)v1.y; pi[2] = (__bf16)v2.y; pi[3] = (__bf16)v3.y;
    size_t rowm = (size_t)(b * 1024 + t0 + row) * 1024 + f0 + chunk * 4;
    *(bf16x4*)(A + rowm) = pr;
    *(bf16x4*)(A + rowm + 512) = pi;
  }
  // Nyquist partial over this block's 64 freqs for each of 64 t's
  float p = 0.f;
#pragma unroll
  for (int i = 0; i < 16; ++i) {
    int fl = th * 16 + i;
    int f = f0 + fl;
    float wgt = (f == 0) ? 1.f : ((f & 1) ? -2.f : 2.f);
    p += wgt * tile[fl][tl].x;
  }
  red[th][tl] = p;
  __syncthreads();
  if (tid < 64) {
    float s4 = red[0][tid] + red[1][tid] + red[2][tid] + red[3][tid];
    if (fy == 0) {
      float rv = x[(((size_t)b * 513 + 512) * 1024 + t0 + tid) * 2];
      re512[b * 1024 + t0 + tid] = rv;
      s4 += rv;
    }
    slices[(size_t)fy * MM + b * 1024 + t0 + tid] = s4;
  }
}

// 256x256 tile, BK=64, 8 waves (2Mx4N), 8-phase counted-vmcnt schedule (T3+T4),
// full 3-bit slot swizzle: LDS[row][slot] = G[row][slot ^ (row&7)] (16B slots),
// applied via pre-swizzled global source (rule 21); fragment reads XOR the same.
// setprio around MFMA clusters (T5), XCD swizzle (T1). Epilogue adds rank-1
// f=512 term and stores C (bf16) via LDS bounce.
__global__ __launch_bounds__(512, 1) void gemm8(
    const __hip_bfloat16* __restrict__ A, const __hip_bfloat16* __restrict__ Bp,
    const float* __restrict__ re512, const float* __restrict__ s_tab,
    __hip_bfloat16* __restrict__ C) {
  __shared__ __align__(16) __hip_bfloat16 smem[65536];  // 128 KB
  int tid = threadIdx.x, lane = tid & 63, wv = tid >> 6;
  int wr = wv >> 2, wc = wv & 3;
  int nf = (blockIdx.x & 7) * 32 + (blockIdx.x >> 3);   // XCD swizzle, 256%8==0
  int M0 = (nf & 63) * 256, N0 = (nf >> 6) * 256;

  __hip_bfloat16* sA0 = smem;
  __hip_bfloat16* sA1 = smem + 16384;
  __hip_bfloat16* sB0 = smem + 32768;
  __hip_bfloat16* sB1 = smem + 49152;

  f32x4 acc[8][4] = {};

#define SG(X, R0, KT, G, LB)                                                   \
  {                                                                            \
    int r_ = (G) * 64 + (tid >> 3);                                            \
    int s_ = (((tid & 7) ^ (r_ & 7)) * 8);                                     \
    gload_lds16((X) + (size_t)((R0) + r_) * 1024 + (KT) * 64 + s_,             \
                (LB) + (G) * 4096 + tid * 8);                                  \
  }
#define VMCNT(N) asm volatile("s_waitcnt vmcnt(" #N ")" ::: "memory")
#define BAR() __builtin_amdgcn_s_barrier()

#define LOADA(Q)                                                               \
  _Pragma("unroll") for (int j = 0; j < 2; ++j) {                              \
    int row = wr * 128 + (2 * (Q) + j) * 16 + (lane & 15);                     \
    _Pragma("unroll") for (int ks = 0; ks < 2; ++ks)                           \
        af[j][ks] = *(const bf16x8*)&cA[row * 64 +                             \
            (((ks * 4 + (lane >> 4)) ^ (row & 7)) * 8)];                       \
  }
#define MFMAQ(Q)                                                               \
  __builtin_amdgcn_s_setprio(1);                                               \
  _Pragma("unroll") for (int j = 0; j < 2; ++j)                                \
  _Pragma("unroll") for (int ks = 0; ks < 2; ++ks)                             \
  _Pragma("unroll") for (int ni = 0; ni < 4; ++ni)                             \
      acc[2 * (Q) + j][ni] = __builtin_amdgcn_mfma_f32_16x16x32_bf16(          \
          af[j][ks], bfr[ks][ni], acc[2 * (Q) + j][ni], 0, 0, 0);              \
  __builtin_amdgcn_s_setprio(0);

  // prologue: tile 0 -> buf0 (order: B g0..g3, A g0,g2 then g1,g3)
  SG(Bp, N0, 0, 0, sB0); SG(Bp, N0, 0, 1, sB0);
  SG(Bp, N0, 0, 2, sB0); SG(Bp, N0, 0, 3, sB0);
  SG(A, M0, 0, 0, sA0);  SG(A, M0, 0, 2, sA0);
  SG(A, M0, 0, 1, sA0);  SG(A, M0, 0, 3, sA0);
  VMCNT(2);   // B g0..3 + A g0,g2 landed; A g1,g3 still in flight
  BAR();

  for (int t = 0; t < 16; ++t) {
    __hip_bfloat16* cA = (t & 1) ? sA1 : sA0;
    __hip_bfloat16* cB = (t & 1) ? sB1 : sB0;
    __hip_bfloat16* nA = (t & 1) ? sA0 : sA1;
    __hip_bfloat16* nB = (t & 1) ? sB0 : sB1;
    int k1 = t + 1;
    bf16x8 bfr[2][4], af[2][2];

    // ---- phase 0: B-frags (whole tile) + A mi0,1; stage next B g0,g1
#pragma unroll
    for (int ni = 0; ni < 4; ++ni) {
      int row = wc * 64 + ni * 16 + (lane & 15);
#pragma unroll
      for (int ks = 0; ks < 2; ++ks)
        bfr[ks][ni] = *(const bf16x8*)&cB[row * 64 +
            (((ks * 4 + (lane >> 4)) ^ (row & 7)) * 8)];
    }
    LOADA(0);
    if (t < 15) { SG(Bp, N0, k1, 0, nB); SG(Bp, N0, k1, 1, nB); }
    BAR();
    MFMAQ(0);
    BAR();
    // ---- phase 1: A mi2,3; stage next B g2,g3; mid-tile wait for own A g1,g3
    LOADA(1);
    if (t < 15) { SG(Bp, N0, k1, 2, nB); SG(Bp, N0, k1, 3, nB); }
    BAR();
    MFMAQ(1);
    if (t < 15) { VMCNT(4); } else { VMCNT(0); }
    BAR();
    // ---- phase 2: A mi4,5; stage next A g0,g2
    LOADA(2);
    if (t < 15) { SG(A, M0, k1, 0, nA); SG(A, M0, k1, 2, nA); }
    BAR();
    MFMAQ(2);
    BAR();
    // ---- phase 3: A mi6,7; stage next A g1,g3; boundary wait
    LOADA(3);
    if (t < 15) { SG(A, M0, k1, 1, nA); SG(A, M0, k1, 3, nA); }
    BAR();
    MFMAQ(3);
    if (t < 15) { VMCNT(2); }
    BAR();
  }

  // epilogue: add rank-1 term, bounce through LDS, coalesced bf16 stores
  __hip_bfloat16* ct = smem;
  float snv[4];
#pragma unroll
  for (int ni = 0; ni < 4; ++ni)
    snv[ni] = s_tab[(N0 + wc * 64 + ni * 16 + (lane & 15)) & 511];
#pragma unroll
  for (int mi = 0; mi < 8; ++mi) {
    int rbase = wr * 128 + mi * 16 + (lane >> 4) * 4;
    float4 rv = *(const float4*)&re512[M0 + rbase];
#pragma unroll
    for (int ni = 0; ni < 4; ++ni) {
      int col = wc * 64 + ni * 16 + (lane & 15);
#pragma unroll
      for (int r = 0; r < 4; ++r) {
        float val = acc[mi][ni][r] + ((const float*)&rv)[r] * snv[ni];
        ct[(rbase + r) * 256 + col] = __float2bfloat16(val);
      }
    }
  }
  BAR();
#pragma unroll
  for (int k = 0; k < 16; ++k) {
    int row = k * 16 + (tid >> 5);
    int c0 = (tid & 31) * 8;
    *(int4*)(C + (size_t)(M0 + row) * 1024 + N0 + c0) = *(const int4*)&ct[row * 256 + c0];
  }
#undef SG
#undef VMCNT
#undef BAR
#undef LOADA
#undef MFMAQ
}

// out[b][l] = sum_t frame[t][l-256t]; frame[j]: j<512 -> C[m][j], j==512 ->
// (sum_y slices[y][m])*CQ, j>512 -> C[m][1536-j]
__global__ void ola(const __hip_bfloat16* __restrict__ C, const float* __restrict__ slices,
                    float* __restrict__ out, int total) {
  int idx = blockIdx.x * blockDim.x + threadIdx.x;
  int stride = gridDim.x * blockDim.x;
  for (; idx < total; idx += stride) {
    int b = idx / LOUT;
    int l = idx - b * LOUT;
    int thi = l >> 8; if (thi > NT - 1) thi = NT - 1;
    int tlo = (l - 768) >> 8; if (tlo < 0) tlo = 0;
    float s = 0.f;
    for (int t = tlo; t <= thi; ++t) {
      int j = l - (t << 8);
      size_t m = (size_t)b * NT + t;
      if (j < 512) s += __bfloat162float(C[m * 1024 + j]);
      else if (j > 512) s += __bfloat162float(C[m * 1024 + 1536 - j]);
      else {
        float s5 = 0.f;
#pragma unroll
        for (int y = 0; y < 8; ++y) s5 += slices[(size_t)y * MM + m];
        s += s5 * CQ;
      }
    }
    out[idx] = s;
  }
}

extern "C" void kernel_launch(void* const* d_in, const int* in_sizes, int n_in,
                              void* d_out, int out_size, void* d_ws, size_t ws_size,
                              hipStream_t stream) {
  (void)in_sizes; (void)n_in; (void)out_size; (void)ws_size;
  const float* x = (const float*)d_in[0];
  float* out = (float*)d_out;
  char* ws = (char*)d_ws;
  size_t oA  = 0;
  size_t oB  = oA + (size_t)MM * 1024 * 2;         // 33.55 MB
  size_t oS  = oB + (size_t)1024 * 1024 * 2;       // +2 MB
  size_t oR5 = oS + 512 * 4;
  size_t oSl = oR5 + (size_t)MM * 4;
  size_t oC  = oSl + (size_t)MM * 8 * 4;           // 8 slices x 64 KB
  __hip_bfloat16* A  = (__hip_bfloat16*)(ws + oA);
  __hip_bfloat16* Bp = (__hip_bfloat16*)(ws + oB);
  float* s_tab = (float*)(ws + oS);
  float* re512 = (float*)(ws + oR5);
  float* slices = (float*)(ws + oSl);
  __hip_bfloat16* C  = (__hip_bfloat16*)(ws + oC);

  prep<<<dim3(PACK_BLOCKS + 4096), dim3(256), 0, stream>>>(x, A, re512, slices, Bp, s_tab);
  gemm8<<<dim3(256), dim3(512), 0, stream>>>(A, Bp, re512, s_tab, C);
  ola<<<dim3(2048), dim3(256), 0, stream>>>(C, slices, out, NB * LOUT);
}

// Round 12
// 69.887 us; speedup vs baseline: 1.4883x; 1.1116x over previous
//
#include <hip/hip_runtime.h>
#include <hip/hip_bf16.h>

#define HOP 256
#define NB 16
#define NT 1024
#define MM (NB*NT)                 // 16384
#define LOUT ((NT-1)*HOP + 1024)   // 262912
#define CQ (2.0f/(3.0f*1024.0f))   // (HOP/sum(win^2))/NFFT
#define PACK_BLOCKS 2048           // 16 b x 8 f-tiles x 16 t-tiles

typedef __bf16 bf16x8 __attribute__((ext_vector_type(8)));
typedef float f32x4 __attribute__((ext_vector_type(4)));

__device__ __forceinline__ void gload_lds16(const void* g, void* l) {
  __builtin_amdgcn_global_load_lds(
      (const __attribute__((address_space(1))) void*)g,
      (__attribute__((address_space(3))) void*)l, 16, 0, 0);
}

// Fused prep.
// Blocks [0,PACK_BLOCKS): pack x -> A' bf16 (A'[m][c]: c<512 re x[b][c][t],
//   c>=512 im x[b][c-512][t]) + re512[m] = x[b][512][t][0].
// Blocks [PACK_BLOCKS,+4096): B''[j][c] = sc_f*win[j]*CQ*(c<512 ? cos(2pi f j/1024)
//   : -sin(2pi f j/1024)), f=c&511 — DIRECT rows: C[m][j] = frame[j] for all j.
//   Row 512 is the Nyquist row (sin(pi f)=0 so U+V=U-V there). Row 0 = 0 (win).
//   s_tab[j] = (-1)^j*win[j]*CQ (f=512 rank-1 column factor, all 1024 j).
__global__ void prep(const float* __restrict__ x, __hip_bfloat16* __restrict__ A,
                     float* __restrict__ re512,
                     __hip_bfloat16* __restrict__ Bp, float* __restrict__ s_tab) {
  int tid = threadIdx.x;
  if (blockIdx.x >= PACK_BLOCKS) {
    int idx = (blockIdx.x - PACK_BLOCKS) * 256 + tid;   // [0, 1024*1024)
    int j = idx >> 10, c = idx & 1023;
    int f = c & 511;
    const float w0 = 6.283185307179586f / 1024.f;
    int ph = (f * j) & 1023;
    float si, co;
    __sincosf((float)ph * w0, &si, &co);
    float wn = 0.5f - 0.5f * __cosf((float)j * w0);
    float sc = (f == 0) ? 1.f : 2.f;
    float bb = sc * CQ * wn;
    float v = (c < 512) ? co * bb : -si * bb;
    Bp[idx] = __float2bfloat16(v);
    if (idx < 1024) {
      float wn2 = 0.5f - 0.5f * __cosf((float)idx * w0);
      s_tab[idx] = ((idx & 1) ? -1.f : 1.f) * wn2 * CQ;
    }
    return;
  }
  __shared__ float2 tile[64][65];
  int w = blockIdx.x;
  int b = w >> 7, fy = (w >> 4) & 7, tx = w & 15;
  int f0 = fy * 64, t0 = tx * 64;
  int tl = tid & 63, th = tid >> 6;
#pragma unroll
  for (int r = 0; r < 16; ++r) {
    int fl = r * 4 + th;
    tile[fl][tl] = *(const float2*)(x + (((size_t)b * 513 + f0 + fl) * 1024 + (t0 + tl)) * 2);
  }
  __syncthreads();
  int row = tid >> 2;
#pragma unroll
  for (int i = 0; i < 2; ++i) {
    int g = (tid & 3) * 2 + i;       // 0..7 -> 8 consecutive f's
    bf16x8 pr, pi;
#pragma unroll
    for (int e = 0; e < 8; ++e) {
      float2 v = tile[g * 8 + e][row];
      pr[e] = (__bf16)v.x;
      pi[e] = (__bf16)v.y;
    }
    size_t rowm = (size_t)(b * 1024 + t0 + row) * 1024 + f0 + g * 8;
    *(bf16x8*)(A + rowm) = pr;
    *(bf16x8*)(A + rowm + 512) = pi;
  }
  if (fy == 0 && tid < 64)
    re512[b * 1024 + t0 + tid] = x[(((size_t)b * 513 + 512) * 1024 + t0 + tid) * 2];
}

// 256x256 tile, BK=64, 8 waves (2Mx4N), 8-phase counted-vmcnt schedule (T3+T4),
// full 3-bit slot swizzle (pre-swizzled source + matching fragment XOR, rule 21),
// setprio around MFMA clusters (T5), XCD swizzle (T1). Epilogue adds rank-1
// f=512 term and stores C (bf16) via LDS bounce. C[m][j] = frame[j] directly.
__global__ __launch_bounds__(512, 1) void gemm8(
    const __hip_bfloat16* __restrict__ A, const __hip_bfloat16* __restrict__ Bp,
    const float* __restrict__ re512, const float* __restrict__ s_tab,
    __hip_bfloat16* __restrict__ C) {
  __shared__ __align__(16) __hip_bfloat16 smem[65536];  // 128 KB
  int tid = threadIdx.x, lane = tid & 63, wv = tid >> 6;
  int wr = wv >> 2, wc = wv & 3;
  int nf = (blockIdx.x & 7) * 32 + (blockIdx.x >> 3);   // XCD swizzle, 256%8==0
  int M0 = (nf & 63) * 256, N0 = (nf >> 6) * 256;

  __hip_bfloat16* sA0 = smem;
  __hip_bfloat16* sA1 = smem + 16384;
  __hip_bfloat16* sB0 = smem + 32768;
  __hip_bfloat16* sB1 = smem + 49152;

  f32x4 acc[8][4] = {};

#define SG(X, R0, KT, G, LB)                                                   \
  {                                                                            \
    int r_ = (G) * 64 + (tid >> 3);                                            \
    int s_ = (((tid & 7) ^ (r_ & 7)) * 8);                                     \
    gload_lds16((X) + (size_t)((R0) + r_) * 1024 + (KT) * 64 + s_,             \
                (LB) + (G) * 4096 + tid * 8);                                  \
  }
#define VMCNT(N) asm volatile("s_waitcnt vmcnt(" #N ")" ::: "memory")
#define BAR() __builtin_amdgcn_s_barrier()

#define LOADA(Q)                                                               \
  _Pragma("unroll") for (int j = 0; j < 2; ++j) {                              \
    int row = wr * 128 + (2 * (Q) + j) * 16 + (lane & 15);                     \
    _Pragma("unroll") for (int ks = 0; ks < 2; ++ks)                           \
        af[j][ks] = *(const bf16x8*)&cA[row * 64 +                             \
            (((ks * 4 + (lane >> 4)) ^ (row & 7)) * 8)];                       \
  }
#define MFMAQ(Q)                                                               \
  __builtin_amdgcn_s_setprio(1);                                               \
  _Pragma("unroll") for (int j = 0; j < 2; ++j)                                \
  _Pragma("unroll") for (int ks = 0; ks < 2; ++ks)                             \
  _Pragma("unroll") for (int ni = 0; ni < 4; ++ni)                             \
      acc[2 * (Q) + j][ni] = __builtin_amdgcn_mfma_f32_16x16x32_bf16(          \
          af[j][ks], bfr[ks][ni], acc[2 * (Q) + j][ni], 0, 0, 0);              \
  __builtin_amdgcn_s_setprio(0);

  // prologue: tile 0 -> buf0 (order: B g0..g3, A g0,g2 then g1,g3)
  SG(Bp, N0, 0, 0, sB0); SG(Bp, N0, 0, 1, sB0);
  SG(Bp, N0, 0, 2, sB0); SG(Bp, N0, 0, 3, sB0);
  SG(A, M0, 0, 0, sA0);  SG(A, M0, 0, 2, sA0);
  SG(A, M0, 0, 1, sA0);  SG(A, M0, 0, 3, sA0);
  VMCNT(2);   // B g0..3 + A g0,g2 landed; A g1,g3 still in flight
  BAR();

  for (int t = 0; t < 16; ++t) {
    __hip_bfloat16* cA = (t & 1) ? sA1 : sA0;
    __hip_bfloat16* cB = (t & 1) ? sB1 : sB0;
    __hip_bfloat16* nA = (t & 1) ? sA0 : sA1;
    __hip_bfloat16* nB = (t & 1) ? sB0 : sB1;
    int k1 = t + 1;
    bf16x8 bfr[2][4], af[2][2];

    // ---- phase 0: B-frags (whole tile) + A mi0,1; stage next B g0,g1
#pragma unroll
    for (int ni = 0; ni < 4; ++ni) {
      int row = wc * 64 + ni * 16 + (lane & 15);
#pragma unroll
      for (int ks = 0; ks < 2; ++ks)
        bfr[ks][ni] = *(const bf16x8*)&cB[row * 64 +
            (((ks * 4 + (lane >> 4)) ^ (row & 7)) * 8)];
    }
    LOADA(0);
    if (t < 15) { SG(Bp, N0, k1, 0, nB); SG(Bp, N0, k1, 1, nB); }
    BAR();
    MFMAQ(0);
    BAR();
    // ---- phase 1: A mi2,3; stage next B g2,g3; mid-tile wait
    LOADA(1);
    if (t < 15) { SG(Bp, N0, k1, 2, nB); SG(Bp, N0, k1, 3, nB); }
    BAR();
    MFMAQ(1);
    if (t < 15) { VMCNT(4); } else { VMCNT(0); }
    BAR();
    // ---- phase 2: A mi4,5; stage next A g0,g2
    LOADA(2);
    if (t < 15) { SG(A, M0, k1, 0, nA); SG(A, M0, k1, 2, nA); }
    BAR();
    MFMAQ(2);
    BAR();
    // ---- phase 3: A mi6,7; stage next A g1,g3; boundary wait
    LOADA(3);
    if (t < 15) { SG(A, M0, k1, 1, nA); SG(A, M0, k1, 3, nA); }
    BAR();
    MFMAQ(3);
    if (t < 15) { VMCNT(2); }
    BAR();
  }

  // epilogue: add rank-1 term, bounce through LDS, coalesced bf16 stores
  __hip_bfloat16* ct = smem;
  float snv[4];
#pragma unroll
  for (int ni = 0; ni < 4; ++ni)
    snv[ni] = s_tab[N0 + wc * 64 + ni * 16 + (lane & 15)];
#pragma unroll
  for (int mi = 0; mi < 8; ++mi) {
    int rbase = wr * 128 + mi * 16 + (lane >> 4) * 4;
    float4 rv = *(const float4*)&re512[M0 + rbase];
#pragma unroll
    for (int ni = 0; ni < 4; ++ni) {
      int col = wc * 64 + ni * 16 + (lane & 15);
#pragma unroll
      for (int r = 0; r < 4; ++r) {
        float val = acc[mi][ni][r] + ((const float*)&rv)[r] * snv[ni];
        ct[(rbase + r) * 256 + col] = __float2bfloat16(val);
      }
    }
  }
  BAR();
#pragma unroll
  for (int k = 0; k < 16; ++k) {
    int row = k * 16 + (tid >> 5);
    int c0 = (tid & 31) * 8;
    *(int4*)(C + (size_t)(M0 + row) * 1024 + N0 + c0) = *(const int4*)&ct[row * 256 + c0];
  }
#undef SG
#undef VMCNT
#undef BAR
#undef LOADA
#undef MFMAQ
}

// OLA: out[b][256q+r] = sum_{t=q-3..q, clamped} C[b*1024+t][ (256q+r) - 256t ].
// Since C[m][j] = frame[j] directly, interior q (3..1023) reads 4 contiguous
// aligned bf16x8 spans: cols {r,r+256,r+512,r+768} at rows q..q-3.
// Edge blocks (q<3 or q>=1024) take the clamped scalar path.
__global__ void ola2(const __hip_bfloat16* __restrict__ C, float* __restrict__ out) {
  int q = blockIdx.x;                        // 0..1026
  int b = blockIdx.y * 8 + (threadIdx.x >> 5);
  int r0 = (threadIdx.x & 31) * 8;
  size_t outl = (size_t)b * LOUT + q * 256 + r0;
  if (q >= 3 && q < 1024) {
    size_t mrow = ((size_t)b * 1024 + q) * 1024;
    bf16x8 v0 = *(const bf16x8*)&C[mrow + r0];
    bf16x8 v1 = *(const bf16x8*)&C[mrow - 1024 + 256 + r0];
    bf16x8 v2 = *(const bf16x8*)&C[mrow - 2048 + 512 + r0];
    bf16x8 v3 = *(const bf16x8*)&C[mrow - 3072 + 768 + r0];
    float res[8];
#pragma unroll
    for (int e = 0; e < 8; ++e)
      res[e] = (float)v0[e] + (float)v1[e] + (float)v2[e] + (float)v3[e];
    *(float4*)(out + outl) = make_float4(res[0], res[1], res[2], res[3]);
    *(float4*)(out + outl + 4) = make_float4(res[4], res[5], res[6], res[7]);
    return;
  }
#pragma unroll
  for (int e = 0; e < 8; ++e) {
    int l = q * 256 + r0 + e;
    int thi = l >> 8; if (thi > 1023) thi = 1023;
    int tlo = (l - 768) >> 8; if (tlo < 0) tlo = 0;
    float s = 0.f;
    for (int t = tlo; t <= thi; ++t)
      s += __bfloat162float(C[((size_t)b * 1024 + t) * 1024 + (l - (t << 8))]);
    out[outl + e] = s;
  }
}

extern "C" void kernel_launch(void* const* d_in, const int* in_sizes, int n_in,
                              void* d_out, int out_size, void* d_ws, size_t ws_size,
                              hipStream_t stream) {
  (void)in_sizes; (void)n_in; (void)out_size; (void)ws_size;
  const float* x = (const float*)d_in[0];
  float* out = (float*)d_out;
  char* ws = (char*)d_ws;
  size_t oA  = 0;
  size_t oB  = oA + (size_t)MM * 1024 * 2;         // 33.55 MB
  size_t oS  = oB + (size_t)1024 * 1024 * 2;       // +2 MB
  size_t oR5 = oS + 1024 * 4;
  size_t oC  = oR5 + (size_t)MM * 4;
  __hip_bfloat16* A  = (__hip_bfloat16*)(ws + oA);
  __hip_bfloat16* Bp = (__hip_bfloat16*)(ws + oB);
  float* s_tab = (float*)(ws + oS);
  float* re512 = (float*)(ws + oR5);
  __hip_bfloat16* C  = (__hip_bfloat16*)(ws + oC);

  prep<<<dim3(PACK_BLOCKS + 4096), dim3(256), 0, stream>>>(x, A, re512, Bp, s_tab);
  gemm8<<<dim3(256), dim3(512), 0, stream>>>(A, Bp, re512, s_tab, C);
  ola2<<<dim3(1027, 2), dim3(256), 0, stream>>>(C, out);
}